// Round 5
// baseline (262.091 us; speedup 1.0000x reference)
//
#include <hip/hip_runtime.h>
#include <hip/hip_bf16.h>
#include <stdint.h>

// B=2, S=2048, D=1024, H=16, Hd=64.  Inputs/outputs FP32; internal bf16 MFMA.
// R15 = gemms/cvt unchanged (R8 form).  Attn v9 = v5 numerics (proven P LDS
// round-trip; R14's permlane P failed correctness) with K/V staging DELETED:
// kf/vf load directly from global (L1/L2-resident: per-XCD K+V = 2MB < 4MB L2;
// per-tile 16KB shared by 4 same-wk waves -> L1).  Main loop has ZERO
// barriers -- removes the 64 block-wide rendezvous/block that pinned MfmaUtil
// at ~26% across R11-R13.  Per-wave Ps is private + DS-pipe in-order, so the
// exp->P->PV chain needs no barrier either.  m169 precedent: dropping
// L2-resident V staging was +26%.

typedef __bf16 bf16;
typedef __attribute__((ext_vector_type(8))) __bf16 bf16x8;
typedef __attribute__((ext_vector_type(4))) __bf16 bf16x4;
typedef __attribute__((ext_vector_type(4))) float f32x4;

#define DEVI __device__ __forceinline__

DEVI void gl_lds16(const void* g, void* l) {
  __builtin_amdgcn_global_load_lds(
      (const __attribute__((address_space(1))) void*)g,
      (__attribute__((address_space(3))) void*)l, 16, 0, 0);
}

DEVI bf16x8 load8(const bf16* p) { return *(const bf16x8*)p; }
DEVI bf16x8 load8(const float* p) {
  f32x4 a = *(const f32x4*)p;
  f32x4 b = *(const f32x4*)(p + 4);
  bf16x8 r;
  r[0] = (bf16)a[0]; r[1] = (bf16)a[1]; r[2] = (bf16)a[2]; r[3] = (bf16)a[3];
  r[4] = (bf16)b[0]; r[5] = (bf16)b[1]; r[6] = (bf16)b[2]; r[7] = (bf16)b[3];
  return r;
}

// ---------------------------------------------------------------------------
// fp32 -> bf16 bulk convert.  grid (512, 8): y<4 -> W[y], y>=4 -> x quarter.
// ---------------------------------------------------------------------------
__global__ __launch_bounds__(256)
void cvt_kernel(const float* __restrict__ x,
                const float* __restrict__ w0, const float* __restrict__ w1,
                const float* __restrict__ w2, const float* __restrict__ w3,
                bf16* __restrict__ xb, bf16* __restrict__ wb) {
  const int y = blockIdx.y;
  const float* src;
  bf16* dst;
  if (y < 4) {
    src = (y == 0) ? w0 : (y == 1) ? w1 : (y == 2) ? w2 : w3;
    dst = wb + (size_t)y * 1048576;
  } else {
    src = x + (size_t)(y - 4) * 1048576;
    dst = xb + (size_t)(y - 4) * 1048576;
  }
  const int i = (blockIdx.x * 256 + threadIdx.x) * 8;
  *(bf16x8*)(dst + i) = load8(src + i);
}

// ---------------------------------------------------------------------------
// GEMM (R8-exact): C[m,n] = (sum_k X[m,k]*W[n,k]) * scale[n] [*emul].
// bf16 operands stage via global_load_lds (src-swizzled); fp32 manual.
// three=1 (NTILE=128): 8 n-tiles per W; Q/K -> [B,H,S,64] (Q gets
//   emul=0.125*log2e), V -> transposed [B,H,64,S].
// three=0 (NTILE=64): plain fp32 row-major out.
// ---------------------------------------------------------------------------
template <typename XT, typename WT, int NTILE>
__global__ __launch_bounds__(256, 2)
void gemm_kernel(const XT* __restrict__ X,
                 const WT* __restrict__ W0, const WT* __restrict__ W1,
                 const WT* __restrict__ W2,
                 const float* __restrict__ s0, const float* __restrict__ s1,
                 const float* __restrict__ s2,
                 bf16* __restrict__ o0, bf16* __restrict__ o1,
                 bf16* __restrict__ o2, float* __restrict__ ofp, int three) {
  constexpr int NF = NTILE / 32;
  constexpr bool ASYNC_A = (sizeof(XT) == 2);
  constexpr bool ASYNC_B = (sizeof(WT) == 2);
  __shared__ bf16 As[128 * 32];
  __shared__ bf16 Bs[NTILE * 32];

  const int t = threadIdx.x;
  const int lane = t & 63;
  const int w = t >> 6;
  const int wm = w >> 1, wn = w & 1;
  const int m0 = blockIdx.x * 128;
  const int cl = lane & 15, quad = lane >> 4;

  const WT* Wp; const float* sp; bf16* op; int mode, n0; float emul = 1.f;
  if (three) {
    int which = blockIdx.y >> 3;
    n0 = (blockIdx.y & 7) * 128;
    if (which == 0)      { Wp = W0; sp = s0; op = o0; mode = 1; emul = 0.18033688f; }
    else if (which == 1) { Wp = W1; sp = s1; op = o1; mode = 1; }
    else                 { Wp = W2; sp = s2; op = o2; mode = 2; }
  } else {
    n0 = blockIdx.y * NTILE; Wp = W0; sp = s0; op = o0; mode = 0;
  }

  f32x4 zero = {0.f, 0.f, 0.f, 0.f};
  f32x4 acc[4][NF];
#pragma unroll
  for (int i = 0; i < 4; i++)
#pragma unroll
    for (int j = 0; j < NF; j++) acc[i][j] = zero;

  const int srow = t >> 2;
  const int gcol_sw = ((t & 3) ^ (srow & 3)) * 8;
  const int gcol = (t & 3) * 8;
  const int sphys = (((t & 3) ^ (srow & 3)) << 3);

  for (int k0 = 0; k0 < 1024; k0 += 32) {
    bf16x8 a0, a1, b0, b1;
    if constexpr (!ASYNC_A) {
      a0 = load8(&X[(uint64_t)(m0 + srow) * 1024 + k0 + gcol]);
      a1 = load8(&X[(uint64_t)(m0 + 64 + srow) * 1024 + k0 + gcol]);
    }
    if constexpr (!ASYNC_B) {
      b0 = load8(&Wp[(uint64_t)(n0 + srow) * 1024 + k0 + gcol]);
      if constexpr (NTILE == 128)
        b1 = load8(&Wp[(uint64_t)(n0 + 64 + srow) * 1024 + k0 + gcol]);
    }
    __syncthreads();
    if constexpr (ASYNC_A) {
      gl_lds16(X + (uint64_t)(m0 + srow) * 1024 + k0 + gcol_sw, (char*)As + t * 16);
      gl_lds16(X + (uint64_t)(m0 + 64 + srow) * 1024 + k0 + gcol_sw,
               (char*)As + 4096 + t * 16);
    } else {
      *(bf16x8*)&As[srow * 32 + sphys] = a0;
      *(bf16x8*)&As[(64 + srow) * 32 + sphys] = a1;
    }
    if constexpr (ASYNC_B) {
      gl_lds16(Wp + (uint64_t)(n0 + srow) * 1024 + k0 + gcol_sw, (char*)Bs + t * 16);
      if constexpr (NTILE == 128)
        gl_lds16(Wp + (uint64_t)(n0 + 64 + srow) * 1024 + k0 + gcol_sw,
                 (char*)Bs + 4096 + t * 16);
    } else {
      *(bf16x8*)&Bs[srow * 32 + sphys] = b0;
      if constexpr (NTILE == 128)
        *(bf16x8*)&Bs[(64 + srow) * 32 + sphys] = b1;
    }
    __syncthreads();

    bf16x8 af[4], bfr[NF];
#pragma unroll
    for (int mt = 0; mt < 4; mt++) {
      const int row = wm * 64 + mt * 16 + cl;
      af[mt] = *(const bf16x8*)&As[row * 32 + ((quad ^ (cl & 3)) << 3)];
    }
#pragma unroll
    for (int nt = 0; nt < NF; nt++) {
      const int row = wn * (NF * 16) + nt * 16 + cl;
      bfr[nt] = *(const bf16x8*)&Bs[row * 32 + ((quad ^ (cl & 3)) << 3)];
    }
#pragma unroll
    for (int mt = 0; mt < 4; mt++)
#pragma unroll
      for (int nt = 0; nt < NF; nt++)
        acc[mt][nt] = __builtin_amdgcn_mfma_f32_16x16x32_bf16(af[mt], bfr[nt],
                                                              acc[mt][nt], 0, 0, 0);
  }

#pragma unroll
  for (int nt = 0; nt < NF; nt++) {
    const int gn = n0 + wn * (NF * 16) + nt * 16 + cl;
    const float sc = sp[gn] * emul;
#pragma unroll
    for (int mt = 0; mt < 4; mt++) {
      const int gmb = m0 + wm * 64 + mt * 16 + quad * 4;
#pragma unroll
      for (int r = 0; r < 4; r++) {
        const int gm = gmb + r;
        const float v = acc[mt][nt][r] * sc;
        if (mode == 0) {
          ofp[(uint64_t)gm * 1024 + gn] = v;
        } else {
          const int b = gm >> 11, s = gm & 2047;
          const int h = gn >> 6, hd = gn & 63;
          uint64_t addr;
          if (mode == 1) addr = ((uint64_t)(b * 16 + h) * 2048 + s) * 64 + hd;
          else           addr = ((uint64_t)(b * 16 + h) * 64 + hd) * 2048 + s;
          op[addr] = (bf16)v;
        }
      }
    }
  }
}

// ---------------------------------------------------------------------------
// Flash attention v9: 8 waves (512 threads), wave split 4x2 (wq x wk),
// NO K/V staging -- kf/vf load directly from global (L2-resident), main loop
// has no barriers.  1D grid 512 blocks, XCD-swizzled: xcd=id&7, k=id>>3,
// bh=xcd*4+(k>>4), qt=k&15, q0=qt*128.  Wave (wq in [0,4), wk in {0,1}):
// queries q0+wq*32+mt*16+cl (mt=0..1), keys wk*32+[0,32) of each 64-key tile.
// S^T = mfma(K,Q) K=64; exp2 -> bf16x4 -> per-wave P[32q][32k] (8B-unit
// swizzle, private, DS-pipe in-order -> barrier-free) -> one K=32 PV mfma per
// (mt,nt).  Epilogue: cross-wave (wk) O+l reduction; Obuf aliases Ps region.
// ---------------------------------------------------------------------------
__global__ __launch_bounds__(512, 4)
void attn_kernel(const bf16* __restrict__ Qw, const bf16* __restrict__ Kw,
                 const bf16* __restrict__ Vtw, bf16* __restrict__ Ctx) {
  // loop: Ps = 8 waves x 2KB at [0,16K).  epilogue: Obuf[4][2048] on [0,32K).
  __shared__ char smem[32768];
  __shared__ float Lbuf[256];           // [wq*2+wk][32 queries]

  float* Ob = (float*)smem;             // epilogue alias

  const int t = threadIdx.x, lane = t & 63, w = t >> 6;
  const int cl = lane & 15, quad = lane >> 4;
  const int wq = w >> 1, wk = w & 1;
  bf16* Pw = (bf16*)smem + w * 1024;    // per-wave P[32][32]

  const int id = blockIdx.x;
  const int xcd = id & 7, kk = id >> 3;
  const int bh = xcd * 4 + (kk >> 4);
  const int qt = kk & 15;
  const int b = bh >> 4, h = bh & 15;
  const int q0 = qt * 128;

  const bf16* Qh = Qw + (uint64_t)bh * 2048 * 64;
  const bf16* Kh = Kw + (uint64_t)bh * 2048 * 64;
  const bf16* Vh = Vtw + (uint64_t)bh * 64 * 2048;

  // Q B-fragments: B[k=h*32+quad*8+j][n=cl], queries q0+wq*32+mt*16+cl
  bf16x8 qf[2][2];
#pragma unroll
  for (int mt = 0; mt < 2; mt++) {
    const int r = q0 + wq * 32 + mt * 16 + cl;
    qf[mt][0] = *(const bf16x8*)&Qh[(uint64_t)r * 64 + quad * 8];
    qf[mt][1] = *(const bf16x8*)&Qh[(uint64_t)r * 64 + 32 + quad * 8];
  }

  f32x4 zero = {0.f, 0.f, 0.f, 0.f};
  f32x4 o_acc[2][4];
  float lsum[2] = {0.f, 0.f};
#pragma unroll
  for (int mt = 0; mt < 2; mt++)
#pragma unroll
    for (int nt = 0; nt < 4; nt++) o_acc[mt][nt] = zero;

  for (int k0 = 0; k0 < 2048; k0 += 64) {
    const int kb = k0 + wk * 32;

    // K A-frags direct from global: K[kb+knt*16+cl][hh*32+quad*8+0..8)
    bf16x8 kf[2][2];
#pragma unroll
    for (int knt = 0; knt < 2; knt++)
#pragma unroll
      for (int hh = 0; hh < 2; hh++)
        kf[knt][hh] = load8(&Kh[(uint64_t)(kb + knt * 16 + cl) * 64 +
                                hh * 32 + quad * 8]);
    // V B-frags direct from global: V[nt*16+cl][kb+quad*8+0..8)
    bf16x8 vf[4];
#pragma unroll
    for (int nt = 0; nt < 4; nt++)
      vf[nt] = load8(&Vh[(uint64_t)(nt * 16 + cl) * 2048 + kb + quad * 8]);

    // S^T (log2 units) -> exp2 -> P (per-wave LDS)
#pragma unroll
    for (int mt = 0; mt < 2; mt++) {
#pragma unroll
      for (int knt = 0; knt < 2; knt++) {
        f32x4 s = __builtin_amdgcn_mfma_f32_16x16x32_bf16(kf[knt][0], qf[mt][0],
                                                          zero, 0, 0, 0);
        s = __builtin_amdgcn_mfma_f32_16x16x32_bf16(kf[knt][1], qf[mt][1], s, 0, 0, 0);
        bf16x4 pk;
        float ls = 0.f;
#pragma unroll
        for (int r = 0; r < 4; r++) {
          const float p = __builtin_amdgcn_exp2f(s[r]);
          ls += p;
          pk[r] = (bf16)p;
        }
        lsum[mt] += ls;
        const int row = mt * 16 + cl;
        const int u = knt * 4 + quad;               // 8B unit (4 keys)
        *(bf16x4*)&Pw[row * 32 + ((u ^ (cl & 6)) << 2)] = pk;
      }
    }

    // P A-frags (K=32, wave's 32 keys) + PV
#pragma unroll
    for (int mt = 0; mt < 2; mt++) {
      const int row = mt * 16 + cl;
      bf16x8 pf = *(const bf16x8*)&Pw[row * 32 + (((2 * quad) ^ (cl & 6)) << 2)];
#pragma unroll
      for (int nt = 0; nt < 4; nt++)
        o_acc[mt][nt] = __builtin_amdgcn_mfma_f32_16x16x32_bf16(pf, vf[nt],
                                                                o_acc[mt][nt],
                                                                0, 0, 0);
    }
  }

  // ---- epilogue: per-wave l reduce, then cross-wk O/l combine ----
#pragma unroll
  for (int mt = 0; mt < 2; mt++) {
    float l = lsum[mt];
    l += __shfl_xor(l, 16);
    l += __shfl_xor(l, 32);
    if (lane < 16) Lbuf[w * 32 + mt * 16 + lane] = l;
  }
  __syncthreads();            // all waves' loop P-reads done -> Obuf alias safe
  if (wk == 1) {
#pragma unroll
    for (int mt = 0; mt < 2; mt++)
#pragma unroll
      for (int nt = 0; nt < 4; nt++)
        *(f32x4*)&Ob[wq * 2048 + (mt * 4 + nt) * 256 + lane * 4] = o_acc[mt][nt];
  }
  __syncthreads();
  if (wk == 0) {
#pragma unroll
    for (int mt = 0; mt < 2; mt++) {
      float linv[4];
#pragma unroll
      for (int r = 0; r < 4; r++) {
        const int ql = mt * 16 + quad * 4 + r;
        linv[r] = 1.0f / (Lbuf[(wq * 2) * 32 + ql] + Lbuf[(wq * 2 + 1) * 32 + ql]);
      }
#pragma unroll
      for (int nt = 0; nt < 4; nt++) {
        f32x4 other = *(const f32x4*)&Ob[wq * 2048 + (mt * 4 + nt) * 256 + lane * 4];
#pragma unroll
        for (int r = 0; r < 4; r++) {
          const int q = q0 + wq * 32 + mt * 16 + quad * 4 + r;
          const int hd = nt * 16 + cl;
          Ctx[(uint64_t)(b * 2048 + q) * 1024 + h * 64 + hd] =
              (bf16)((o_acc[mt][nt][r] + other[r]) * linv[r]);
        }
      }
    }
  }
}

// ---------------------------------------------------------------------------
extern "C" void kernel_launch(void* const* d_in, const int* in_sizes, int n_in,
                              void* d_out, int out_size, void* d_ws, size_t ws_size,
                              hipStream_t stream) {
  const float* x  = (const float*)d_in[0];
  const float* Wq = (const float*)d_in[1];
  const float* Wk = (const float*)d_in[2];
  const float* Wv = (const float*)d_in[3];
  const float* Wo = (const float*)d_in[4];
  const float* qs = (const float*)d_in[5];
  const float* ks = (const float*)d_in[6];
  const float* vs = (const float*)d_in[7];
  const float* os = (const float*)d_in[8];
  float* out = (float*)d_out;

  const size_t M4 = 4194304, M1 = 1048576;

  if (ws_size >= (size_t)40 * 1024 * 1024) {
    bf16* xb = (bf16*)d_ws;        // 4M bf16; reused as cw after QKV
    bf16* wb = xb + M4;            // wq|wk|wv|wo
    bf16* qw = wb + M4;
    bf16* kw = qw + M4;
    bf16* vw = kw + M4;
    bf16* cw = xb;

    cvt_kernel<<<dim3(512, 8), 256, 0, stream>>>(x, Wq, Wk, Wv, Wo, xb, wb);
    gemm_kernel<bf16, bf16, 128><<<dim3(32, 24), 256, 0, stream>>>(
        xb, wb, wb + M1, wb + 2 * M1, qs, ks, vs, qw, kw, vw, nullptr, 1);
    attn_kernel<<<512, 512, 0, stream>>>(qw, kw, vw, cw);
    gemm_kernel<bf16, bf16, 64><<<dim3(32, 16), 256, 0, stream>>>(
        cw, wb + 3 * M1, nullptr, nullptr, os, nullptr, nullptr,
        nullptr, nullptr, nullptr, out, 0);
  } else {
    bf16* qw = (bf16*)d_ws;
    bf16* kw = qw + M4;
    bf16* vw = kw + M4;
    bf16* cw = vw + M4;
    gemm_kernel<float, float, 128><<<dim3(32, 24), 256, 0, stream>>>(
        x, Wq, Wk, Wv, qs, ks, vs, qw, kw, vw, nullptr, 1);
    attn_kernel<<<512, 512, 0, stream>>>(qw, kw, vw, cw);
    gemm_kernel<bf16, float, 64><<<dim3(32, 16), 256, 0, stream>>>(
        cw, Wo, nullptr, nullptr, os, nullptr, nullptr,
        nullptr, nullptr, nullptr, out, 0);
  }
}

// Round 7
// 185.890 us; speedup vs baseline: 1.4099x; 1.4099x over previous
//
#include <hip/hip_runtime.h>
#include <hip/hip_bf16.h>
#include <stdint.h>

// B=2, S=2048, D=1024, H=16, Hd=64.  Inputs/outputs FP32; internal bf16 MFMA.
// R17 = R16 resubmitted verbatim (R6 bench died on infra error, no result).
// Attn v10 = v5 (R11 best: 8-wave blocks, 4x2 wq x wk, single-buffered
// 2-barrier loop) with the P LDS round-trip DELETED via matched fragment
// layouts -- no permutation needed: after s = mfma(K,Q), lane (cl,quad)
// holds P[key=knt*16+quad*4+r][q=cl]; a K=32 PV A-frag element j is
// contraction index quad*8+j; choosing the PV contraction ORDER as
// (j<4 ? half0 key quad*4+j : half1 key quad*4+j-4) makes the A-frag exactly
// {pk[0],pk[1]} in registers.  V B-frag follows the same order: two b64
// reads at key offsets wk*32+quad*4 and wk*32+16+quad*4.  DS per wave-tile
// 144 -> 96 cyc; exp->PV chain is register-only.

typedef __bf16 bf16;
typedef __attribute__((ext_vector_type(8))) __bf16 bf16x8;
typedef __attribute__((ext_vector_type(4))) __bf16 bf16x4;
typedef __attribute__((ext_vector_type(4))) float f32x4;

#define DEVI __device__ __forceinline__

DEVI void gl_lds16(const void* g, void* l) {
  __builtin_amdgcn_global_load_lds(
      (const __attribute__((address_space(1))) void*)g,
      (__attribute__((address_space(3))) void*)l, 16, 0, 0);
}

DEVI bf16x8 load8(const bf16* p) { return *(const bf16x8*)p; }
DEVI bf16x8 load8(const float* p) {
  f32x4 a = *(const f32x4*)p;
  f32x4 b = *(const f32x4*)(p + 4);
  bf16x8 r;
  r[0] = (bf16)a[0]; r[1] = (bf16)a[1]; r[2] = (bf16)a[2]; r[3] = (bf16)a[3];
  r[4] = (bf16)b[0]; r[5] = (bf16)b[1]; r[6] = (bf16)b[2]; r[7] = (bf16)b[3];
  return r;
}

// ---------------------------------------------------------------------------
// fp32 -> bf16 bulk convert.  grid (512, 8): y<4 -> W[y], y>=4 -> x quarter.
// ---------------------------------------------------------------------------
__global__ __launch_bounds__(256)
void cvt_kernel(const float* __restrict__ x,
                const float* __restrict__ w0, const float* __restrict__ w1,
                const float* __restrict__ w2, const float* __restrict__ w3,
                bf16* __restrict__ xb, bf16* __restrict__ wb) {
  const int y = blockIdx.y;
  const float* src;
  bf16* dst;
  if (y < 4) {
    src = (y == 0) ? w0 : (y == 1) ? w1 : (y == 2) ? w2 : w3;
    dst = wb + (size_t)y * 1048576;
  } else {
    src = x + (size_t)(y - 4) * 1048576;
    dst = xb + (size_t)(y - 4) * 1048576;
  }
  const int i = (blockIdx.x * 256 + threadIdx.x) * 8;
  *(bf16x8*)(dst + i) = load8(src + i);
}

// ---------------------------------------------------------------------------
// GEMM (R8-exact): C[m,n] = (sum_k X[m,k]*W[n,k]) * scale[n] [*emul].
// bf16 operands stage via global_load_lds (src-swizzled); fp32 manual.
// three=1 (NTILE=128): 8 n-tiles per W; Q/K -> [B,H,S,64] (Q gets
//   emul=0.125*log2e), V -> transposed [B,H,64,S].
// three=0 (NTILE=64): plain fp32 row-major out.
// ---------------------------------------------------------------------------
template <typename XT, typename WT, int NTILE>
__global__ __launch_bounds__(256, 2)
void gemm_kernel(const XT* __restrict__ X,
                 const WT* __restrict__ W0, const WT* __restrict__ W1,
                 const WT* __restrict__ W2,
                 const float* __restrict__ s0, const float* __restrict__ s1,
                 const float* __restrict__ s2,
                 bf16* __restrict__ o0, bf16* __restrict__ o1,
                 bf16* __restrict__ o2, float* __restrict__ ofp, int three) {
  constexpr int NF = NTILE / 32;
  constexpr bool ASYNC_A = (sizeof(XT) == 2);
  constexpr bool ASYNC_B = (sizeof(WT) == 2);
  __shared__ bf16 As[128 * 32];
  __shared__ bf16 Bs[NTILE * 32];

  const int t = threadIdx.x;
  const int lane = t & 63;
  const int w = t >> 6;
  const int wm = w >> 1, wn = w & 1;
  const int m0 = blockIdx.x * 128;
  const int cl = lane & 15, quad = lane >> 4;

  const WT* Wp; const float* sp; bf16* op; int mode, n0; float emul = 1.f;
  if (three) {
    int which = blockIdx.y >> 3;
    n0 = (blockIdx.y & 7) * 128;
    if (which == 0)      { Wp = W0; sp = s0; op = o0; mode = 1; emul = 0.18033688f; }
    else if (which == 1) { Wp = W1; sp = s1; op = o1; mode = 1; }
    else                 { Wp = W2; sp = s2; op = o2; mode = 2; }
  } else {
    n0 = blockIdx.y * NTILE; Wp = W0; sp = s0; op = o0; mode = 0;
  }

  f32x4 zero = {0.f, 0.f, 0.f, 0.f};
  f32x4 acc[4][NF];
#pragma unroll
  for (int i = 0; i < 4; i++)
#pragma unroll
    for (int j = 0; j < NF; j++) acc[i][j] = zero;

  const int srow = t >> 2;
  const int gcol_sw = ((t & 3) ^ (srow & 3)) * 8;
  const int gcol = (t & 3) * 8;
  const int sphys = (((t & 3) ^ (srow & 3)) << 3);

  for (int k0 = 0; k0 < 1024; k0 += 32) {
    bf16x8 a0, a1, b0, b1;
    if constexpr (!ASYNC_A) {
      a0 = load8(&X[(uint64_t)(m0 + srow) * 1024 + k0 + gcol]);
      a1 = load8(&X[(uint64_t)(m0 + 64 + srow) * 1024 + k0 + gcol]);
    }
    if constexpr (!ASYNC_B) {
      b0 = load8(&Wp[(uint64_t)(n0 + srow) * 1024 + k0 + gcol]);
      if constexpr (NTILE == 128)
        b1 = load8(&Wp[(uint64_t)(n0 + 64 + srow) * 1024 + k0 + gcol]);
    }
    __syncthreads();
    if constexpr (ASYNC_A) {
      gl_lds16(X + (uint64_t)(m0 + srow) * 1024 + k0 + gcol_sw, (char*)As + t * 16);
      gl_lds16(X + (uint64_t)(m0 + 64 + srow) * 1024 + k0 + gcol_sw,
               (char*)As + 4096 + t * 16);
    } else {
      *(bf16x8*)&As[srow * 32 + sphys] = a0;
      *(bf16x8*)&As[(64 + srow) * 32 + sphys] = a1;
    }
    if constexpr (ASYNC_B) {
      gl_lds16(Wp + (uint64_t)(n0 + srow) * 1024 + k0 + gcol_sw, (char*)Bs + t * 16);
      if constexpr (NTILE == 128)
        gl_lds16(Wp + (uint64_t)(n0 + 64 + srow) * 1024 + k0 + gcol_sw,
                 (char*)Bs + 4096 + t * 16);
    } else {
      *(bf16x8*)&Bs[srow * 32 + sphys] = b0;
      if constexpr (NTILE == 128)
        *(bf16x8*)&Bs[(64 + srow) * 32 + sphys] = b1;
    }
    __syncthreads();

    bf16x8 af[4], bfr[NF];
#pragma unroll
    for (int mt = 0; mt < 4; mt++) {
      const int row = wm * 64 + mt * 16 + cl;
      af[mt] = *(const bf16x8*)&As[row * 32 + ((quad ^ (cl & 3)) << 3)];
    }
#pragma unroll
    for (int nt = 0; nt < NF; nt++) {
      const int row = wn * (NF * 16) + nt * 16 + cl;
      bfr[nt] = *(const bf16x8*)&Bs[row * 32 + ((quad ^ (cl & 3)) << 3)];
    }
#pragma unroll
    for (int mt = 0; mt < 4; mt++)
#pragma unroll
      for (int nt = 0; nt < NF; nt++)
        acc[mt][nt] = __builtin_amdgcn_mfma_f32_16x16x32_bf16(af[mt], bfr[nt],
                                                              acc[mt][nt], 0, 0, 0);
  }

#pragma unroll
  for (int nt = 0; nt < NF; nt++) {
    const int gn = n0 + wn * (NF * 16) + nt * 16 + cl;
    const float sc = sp[gn] * emul;
#pragma unroll
    for (int mt = 0; mt < 4; mt++) {
      const int gmb = m0 + wm * 64 + mt * 16 + quad * 4;
#pragma unroll
      for (int r = 0; r < 4; r++) {
        const int gm = gmb + r;
        const float v = acc[mt][nt][r] * sc;
        if (mode == 0) {
          ofp[(uint64_t)gm * 1024 + gn] = v;
        } else {
          const int b = gm >> 11, s = gm & 2047;
          const int h = gn >> 6, hd = gn & 63;
          uint64_t addr;
          if (mode == 1) addr = ((uint64_t)(b * 16 + h) * 2048 + s) * 64 + hd;
          else           addr = ((uint64_t)(b * 16 + h) * 64 + hd) * 2048 + s;
          op[addr] = (bf16)v;
        }
      }
    }
  }
}

// ---------------------------------------------------------------------------
// Flash attention v10: 8 waves (512 threads), wave split 4x2 (wq x wk),
// single-buffered 2-barrier loop (v5 structure), P entirely in registers via
// matched fragment layouts (no LDS P, no permute).
// 1D grid 512 blocks, XCD-swizzled: xcd=id&7, k=id>>3, bh=xcd*4+(k>>4),
// qt=k&15, q0=qt*128.  Wave (wq in [0,4), wk in {0,1}): queries
// q0+wq*32+mt*16+cl (mt=0..1), keys wk*32+[0,32) of each 64-key tile.
// Per mt: s_knt = mfma(K_half,Q) (K=64 over d) -> exp2 -> pk[knt] bf16x4;
// PV contraction order c=quad*8+j defined as (j<4 ? half0 key quad*4+j :
// half1 key quad*4+j-4), so A-frag = {pk[0],pk[1]} and B-frag = two b64
// reads of Vs at key offsets wk*32+quad*4 / wk*32+16+quad*4.
// Epilogue: cross-wave (wk) O+l reduction; Obuf aliases the K/V region.
// ---------------------------------------------------------------------------
__global__ __launch_bounds__(512, 4)
void attn_kernel(const bf16* __restrict__ Qw, const bf16* __restrict__ Kw,
                 const bf16* __restrict__ Vtw, bf16* __restrict__ Ctx) {
  // loop: [0,8K) Ks | [8K,16K) Vs.  epilogue: Obuf[4][2048] fp32 on [0,32K).
  __shared__ char smem[32768];
  __shared__ float Lbuf[256];           // [wq*2+wk][32 queries]

  bf16* Ks = (bf16*)smem;               // [key][d], chunk c^(key&7)
  bf16* Vs = (bf16*)(smem + 8192);      // [hd][key], chunk c^(hd&7)
  float* Ob = (float*)smem;             // epilogue alias

  const int t = threadIdx.x, lane = t & 63, w = t >> 6;
  const int cl = lane & 15, quad = lane >> 4;
  const int wq = w >> 1, wk = w & 1;

  const int id = blockIdx.x;
  const int xcd = id & 7, kk = id >> 3;
  const int bh = xcd * 4 + (kk >> 4);
  const int qt = kk & 15;
  const int b = bh >> 4, h = bh & 15;
  const int q0 = qt * 128;

  const bf16* Qh = Qw + (uint64_t)bh * 2048 * 64;
  const bf16* Kh = Kw + (uint64_t)bh * 2048 * 64;
  const bf16* Vh = Vtw + (uint64_t)bh * 64 * 2048;

  // Q B-fragments: B[k=h*32+quad*8+j][n=cl], queries q0+wq*32+mt*16+cl
  bf16x8 qf[2][2];
#pragma unroll
  for (int mt = 0; mt < 2; mt++) {
    const int r = q0 + wq * 32 + mt * 16 + cl;
    qf[mt][0] = *(const bf16x8*)&Qh[(uint64_t)r * 64 + quad * 8];
    qf[mt][1] = *(const bf16x8*)&Qh[(uint64_t)r * 64 + 32 + quad * 8];
  }

  f32x4 zero = {0.f, 0.f, 0.f, 0.f};
  f32x4 o_acc[2][4];
  float lsum[2] = {0.f, 0.f};
#pragma unroll
  for (int mt = 0; mt < 2; mt++)
#pragma unroll
    for (int nt = 0; nt < 4; nt++) o_acc[mt][nt] = zero;

  const int srow = t >> 3;                         // 0..63
  const int gcol_sw = ((t & 7) ^ (srow & 7)) * 8;  // swizzled source col

  // V b64 chunk indices (contraction halves): logical key offsets
  // wk*32+quad*4 (half0) and wk*32+16+quad*4 (half1) -> logical 16B chunk
  // lcA = wk*4 + (quad>>1), lcB = lcA + 2; 8B sub = quad&1.
  const int lcA = wk * 4 + (quad >> 1);
  const int sub = (quad & 1) << 2;                 // element offset (4 bf16)

  for (int k0 = 0; k0 < 2048; k0 += 64) {
    __syncthreads();
    gl_lds16(Kh + (uint64_t)(k0 + srow) * 64 + gcol_sw, (char*)Ks + t * 16);
    gl_lds16(Vh + (uint64_t)srow * 2048 + k0 + gcol_sw, (char*)Vs + t * 16);
    __syncthreads();   // tiles resident

    // K A-frags for this wave's 32-key half
    bf16x8 kf[2][2];
#pragma unroll
    for (int knt = 0; knt < 2; knt++) {
      const int krow = wk * 32 + knt * 16 + cl;
#pragma unroll
      for (int hh = 0; hh < 2; hh++)
        kf[knt][hh] = *(const bf16x8*)&Ks[krow * 64 +
                                          (((hh * 4 + quad) ^ (cl & 7)) << 3)];
    }
    // V B-frags in the custom contraction order: element j<4 -> half0 key
    // quad*4+j, j>=4 -> half1 key quad*4+j-4 (row hd = nt*16+cl).
    bf16x8 vf[4];
#pragma unroll
    for (int nt = 0; nt < 4; nt++) {
      const int vrow = (nt * 16 + cl) * 64;
      union { bf16x4 h[2]; bf16x8 v; } vfu;
      vfu.h[0] = *(const bf16x4*)&Vs[vrow + ((lcA ^ (cl & 7)) << 3) + sub];
      vfu.h[1] = *(const bf16x4*)&Vs[vrow + (((lcA + 2) ^ (cl & 7)) << 3) + sub];
      vf[nt] = vfu.v;
    }

    // Per mt: S^T (log2 units) -> exp2 -> pk (registers) -> PV
#pragma unroll
    for (int mt = 0; mt < 2; mt++) {
      bf16x4 pk[2];
#pragma unroll
      for (int knt = 0; knt < 2; knt++) {
        f32x4 s = __builtin_amdgcn_mfma_f32_16x16x32_bf16(kf[knt][0], qf[mt][0],
                                                          zero, 0, 0, 0);
        s = __builtin_amdgcn_mfma_f32_16x16x32_bf16(kf[knt][1], qf[mt][1], s, 0, 0, 0);
        float ls = 0.f;
#pragma unroll
        for (int r = 0; r < 4; r++) {
          const float p = __builtin_amdgcn_exp2f(s[r]);
          ls += p;
          pk[knt][r] = (bf16)p;
        }
        lsum[mt] += ls;
      }
      union { bf16x4 h[2]; bf16x8 v; } pf;
      pf.h[0] = pk[0];   // half0 keys quad*4+0..3  (contraction j=0..3)
      pf.h[1] = pk[1];   // half1 keys quad*4+0..3  (contraction j=4..7)
#pragma unroll
      for (int nt = 0; nt < 4; nt++)
        o_acc[mt][nt] = __builtin_amdgcn_mfma_f32_16x16x32_bf16(pf.v, vf[nt],
                                                                o_acc[mt][nt],
                                                                0, 0, 0);
    }
  }

  // ---- epilogue: per-wave l reduce, then cross-wk O/l combine ----
#pragma unroll
  for (int mt = 0; mt < 2; mt++) {
    float l = lsum[mt];
    l += __shfl_xor(l, 16);
    l += __shfl_xor(l, 32);
    if (lane < 16) Lbuf[w * 32 + mt * 16 + lane] = l;
  }
  __syncthreads();            // loop reads done -> smem reusable for Obuf
  if (wk == 1) {
#pragma unroll
    for (int mt = 0; mt < 2; mt++)
#pragma unroll
      for (int nt = 0; nt < 4; nt++)
        *(f32x4*)&Ob[wq * 2048 + (mt * 4 + nt) * 256 + lane * 4] = o_acc[mt][nt];
  }
  __syncthreads();
  if (wk == 0) {
#pragma unroll
    for (int mt = 0; mt < 2; mt++) {
      float linv[4];
#pragma unroll
      for (int r = 0; r < 4; r++) {
        const int ql = mt * 16 + quad * 4 + r;
        linv[r] = 1.0f / (Lbuf[(wq * 2) * 32 + ql] + Lbuf[(wq * 2 + 1) * 32 + ql]);
      }
#pragma unroll
      for (int nt = 0; nt < 4; nt++) {
        f32x4 other = *(const f32x4*)&Ob[wq * 2048 + (mt * 4 + nt) * 256 + lane * 4];
#pragma unroll
        for (int r = 0; r < 4; r++) {
          const int q = q0 + wq * 32 + mt * 16 + quad * 4 + r;
          const int hd = nt * 16 + cl;
          Ctx[(uint64_t)(b * 2048 + q) * 1024 + h * 64 + hd] =
              (bf16)((o_acc[mt][nt][r] + other[r]) * linv[r]);
        }
      }
    }
  }
}

// ---------------------------------------------------------------------------
extern "C" void kernel_launch(void* const* d_in, const int* in_sizes, int n_in,
                              void* d_out, int out_size, void* d_ws, size_t ws_size,
                              hipStream_t stream) {
  const float* x  = (const float*)d_in[0];
  const float* Wq = (const float*)d_in[1];
  const float* Wk = (const float*)d_in[2];
  const float* Wv = (const float*)d_in[3];
  const float* Wo = (const float*)d_in[4];
  const float* qs = (const float*)d_in[5];
  const float* ks = (const float*)d_in[6];
  const float* vs = (const float*)d_in[7];
  const float* os = (const float*)d_in[8];
  float* out = (float*)d_out;

  const size_t M4 = 4194304, M1 = 1048576;

  if (ws_size >= (size_t)40 * 1024 * 1024) {
    bf16* xb = (bf16*)d_ws;        // 4M bf16; reused as cw after QKV
    bf16* wb = xb + M4;            // wq|wk|wv|wo
    bf16* qw = wb + M4;
    bf16* kw = qw + M4;
    bf16* vw = kw + M4;
    bf16* cw = xb;

    cvt_kernel<<<dim3(512, 8), 256, 0, stream>>>(x, Wq, Wk, Wv, Wo, xb, wb);
    gemm_kernel<bf16, bf16, 128><<<dim3(32, 24), 256, 0, stream>>>(
        xb, wb, wb + M1, wb + 2 * M1, qs, ks, vs, qw, kw, vw, nullptr, 1);
    attn_kernel<<<512, 512, 0, stream>>>(qw, kw, vw, cw);
    gemm_kernel<bf16, bf16, 64><<<dim3(32, 16), 256, 0, stream>>>(
        cw, wb + 3 * M1, nullptr, nullptr, os, nullptr, nullptr,
        nullptr, nullptr, nullptr, out, 0);
  } else {
    bf16* qw = (bf16*)d_ws;
    bf16* kw = qw + M4;
    bf16* vw = kw + M4;
    bf16* cw = vw + M4;
    gemm_kernel<float, float, 128><<<dim3(32, 24), 256, 0, stream>>>(
        x, Wq, Wk, Wv, qs, ks, vs, qw, kw, vw, nullptr, 1);
    attn_kernel<<<512, 512, 0, stream>>>(qw, kw, vw, cw);
    gemm_kernel<bf16, float, 64><<<dim3(32, 16), 256, 0, stream>>>(
        cw, Wo, nullptr, nullptr, os, nullptr, nullptr,
        nullptr, nullptr, nullptr, out, 0);
  }
}

// Round 8
// 185.062 us; speedup vs baseline: 1.4162x; 1.0045x over previous
//
#include <hip/hip_runtime.h>
#include <hip/hip_bf16.h>
#include <stdint.h>

// B=2, S=2048, D=1024, H=16, Hd=64.  Inputs/outputs FP32; internal bf16 MFMA.
// R18 = R17 (attn v10, register-resident P, 185.9us total / 46.1us attn) +
// V KEY-PERMUTE: the mode-2 GEMM writes V^T with keys permuted within each
// 32-block (p = qd*8 + knt*4 + r for s-bits r=s&3, qd=(s>>2)&3, knt=(s>>4)&1)
// so the PV B-frag is ONE contiguous b128 read at chunk (wk*4+quad)^(cl&7) --
// byte-identical to v5's conflict-benign vf pattern -- instead of R17's two
// aliasing b64 reads (which doubled bank conflicts to 4.19M).  LDS reads per
// wave-tile 12 -> 8; permute is free (index remap in the GEMM epilogue).

typedef __bf16 bf16;
typedef __attribute__((ext_vector_type(8))) __bf16 bf16x8;
typedef __attribute__((ext_vector_type(4))) __bf16 bf16x4;
typedef __attribute__((ext_vector_type(4))) float f32x4;

#define DEVI __device__ __forceinline__

DEVI void gl_lds16(const void* g, void* l) {
  __builtin_amdgcn_global_load_lds(
      (const __attribute__((address_space(1))) void*)g,
      (__attribute__((address_space(3))) void*)l, 16, 0, 0);
}

DEVI bf16x8 load8(const bf16* p) { return *(const bf16x8*)p; }
DEVI bf16x8 load8(const float* p) {
  f32x4 a = *(const f32x4*)p;
  f32x4 b = *(const f32x4*)(p + 4);
  bf16x8 r;
  r[0] = (bf16)a[0]; r[1] = (bf16)a[1]; r[2] = (bf16)a[2]; r[3] = (bf16)a[3];
  r[4] = (bf16)b[0]; r[5] = (bf16)b[1]; r[6] = (bf16)b[2]; r[7] = (bf16)b[3];
  return r;
}

// ---------------------------------------------------------------------------
// fp32 -> bf16 bulk convert.  grid (512, 8): y<4 -> W[y], y>=4 -> x quarter.
// ---------------------------------------------------------------------------
__global__ __launch_bounds__(256)
void cvt_kernel(const float* __restrict__ x,
                const float* __restrict__ w0, const float* __restrict__ w1,
                const float* __restrict__ w2, const float* __restrict__ w3,
                bf16* __restrict__ xb, bf16* __restrict__ wb) {
  const int y = blockIdx.y;
  const float* src;
  bf16* dst;
  if (y < 4) {
    src = (y == 0) ? w0 : (y == 1) ? w1 : (y == 2) ? w2 : w3;
    dst = wb + (size_t)y * 1048576;
  } else {
    src = x + (size_t)(y - 4) * 1048576;
    dst = xb + (size_t)(y - 4) * 1048576;
  }
  const int i = (blockIdx.x * 256 + threadIdx.x) * 8;
  *(bf16x8*)(dst + i) = load8(src + i);
}

// ---------------------------------------------------------------------------
// GEMM (R8-exact): C[m,n] = (sum_k X[m,k]*W[n,k]) * scale[n] [*emul].
// bf16 operands stage via global_load_lds (src-swizzled); fp32 manual.
// three=1 (NTILE=128): 8 n-tiles per W; Q/K -> [B,H,S,64] (Q gets
//   emul=0.125*log2e), V -> transposed [B,H,64,S] with keys PERMUTED within
//   each 32-block (attn PV contraction order).
// three=0 (NTILE=64): plain fp32 row-major out.
// ---------------------------------------------------------------------------
template <typename XT, typename WT, int NTILE>
__global__ __launch_bounds__(256, 2)
void gemm_kernel(const XT* __restrict__ X,
                 const WT* __restrict__ W0, const WT* __restrict__ W1,
                 const WT* __restrict__ W2,
                 const float* __restrict__ s0, const float* __restrict__ s1,
                 const float* __restrict__ s2,
                 bf16* __restrict__ o0, bf16* __restrict__ o1,
                 bf16* __restrict__ o2, float* __restrict__ ofp, int three) {
  constexpr int NF = NTILE / 32;
  constexpr bool ASYNC_A = (sizeof(XT) == 2);
  constexpr bool ASYNC_B = (sizeof(WT) == 2);
  __shared__ bf16 As[128 * 32];
  __shared__ bf16 Bs[NTILE * 32];

  const int t = threadIdx.x;
  const int lane = t & 63;
  const int w = t >> 6;
  const int wm = w >> 1, wn = w & 1;
  const int m0 = blockIdx.x * 128;
  const int cl = lane & 15, quad = lane >> 4;

  const WT* Wp; const float* sp; bf16* op; int mode, n0; float emul = 1.f;
  if (three) {
    int which = blockIdx.y >> 3;
    n0 = (blockIdx.y & 7) * 128;
    if (which == 0)      { Wp = W0; sp = s0; op = o0; mode = 1; emul = 0.18033688f; }
    else if (which == 1) { Wp = W1; sp = s1; op = o1; mode = 1; }
    else                 { Wp = W2; sp = s2; op = o2; mode = 2; }
  } else {
    n0 = blockIdx.y * NTILE; Wp = W0; sp = s0; op = o0; mode = 0;
  }

  f32x4 zero = {0.f, 0.f, 0.f, 0.f};
  f32x4 acc[4][NF];
#pragma unroll
  for (int i = 0; i < 4; i++)
#pragma unroll
    for (int j = 0; j < NF; j++) acc[i][j] = zero;

  const int srow = t >> 2;
  const int gcol_sw = ((t & 3) ^ (srow & 3)) * 8;
  const int gcol = (t & 3) * 8;
  const int sphys = (((t & 3) ^ (srow & 3)) << 3);

  for (int k0 = 0; k0 < 1024; k0 += 32) {
    bf16x8 a0, a1, b0, b1;
    if constexpr (!ASYNC_A) {
      a0 = load8(&X[(uint64_t)(m0 + srow) * 1024 + k0 + gcol]);
      a1 = load8(&X[(uint64_t)(m0 + 64 + srow) * 1024 + k0 + gcol]);
    }
    if constexpr (!ASYNC_B) {
      b0 = load8(&Wp[(uint64_t)(n0 + srow) * 1024 + k0 + gcol]);
      if constexpr (NTILE == 128)
        b1 = load8(&Wp[(uint64_t)(n0 + 64 + srow) * 1024 + k0 + gcol]);
    }
    __syncthreads();
    if constexpr (ASYNC_A) {
      gl_lds16(X + (uint64_t)(m0 + srow) * 1024 + k0 + gcol_sw, (char*)As + t * 16);
      gl_lds16(X + (uint64_t)(m0 + 64 + srow) * 1024 + k0 + gcol_sw,
               (char*)As + 4096 + t * 16);
    } else {
      *(bf16x8*)&As[srow * 32 + sphys] = a0;
      *(bf16x8*)&As[(64 + srow) * 32 + sphys] = a1;
    }
    if constexpr (ASYNC_B) {
      gl_lds16(Wp + (uint64_t)(n0 + srow) * 1024 + k0 + gcol_sw, (char*)Bs + t * 16);
      if constexpr (NTILE == 128)
        gl_lds16(Wp + (uint64_t)(n0 + 64 + srow) * 1024 + k0 + gcol_sw,
                 (char*)Bs + 4096 + t * 16);
    } else {
      *(bf16x8*)&Bs[srow * 32 + sphys] = b0;
      if constexpr (NTILE == 128)
        *(bf16x8*)&Bs[(64 + srow) * 32 + sphys] = b1;
    }
    __syncthreads();

    bf16x8 af[4], bfr[NF];
#pragma unroll
    for (int mt = 0; mt < 4; mt++) {
      const int row = wm * 64 + mt * 16 + cl;
      af[mt] = *(const bf16x8*)&As[row * 32 + ((quad ^ (cl & 3)) << 3)];
    }
#pragma unroll
    for (int nt = 0; nt < NF; nt++) {
      const int row = wn * (NF * 16) + nt * 16 + cl;
      bfr[nt] = *(const bf16x8*)&Bs[row * 32 + ((quad ^ (cl & 3)) << 3)];
    }
#pragma unroll
    for (int mt = 0; mt < 4; mt++)
#pragma unroll
      for (int nt = 0; nt < NF; nt++)
        acc[mt][nt] = __builtin_amdgcn_mfma_f32_16x16x32_bf16(af[mt], bfr[nt],
                                                              acc[mt][nt], 0, 0, 0);
  }

#pragma unroll
  for (int nt = 0; nt < NF; nt++) {
    const int gn = n0 + wn * (NF * 16) + nt * 16 + cl;
    const float sc = sp[gn] * emul;
#pragma unroll
    for (int mt = 0; mt < 4; mt++) {
      const int gmb = m0 + wm * 64 + mt * 16 + quad * 4;
#pragma unroll
      for (int r = 0; r < 4; r++) {
        const int gm = gmb + r;
        const float v = acc[mt][nt][r] * sc;
        if (mode == 0) {
          ofp[(uint64_t)gm * 1024 + gn] = v;
        } else {
          const int b = gm >> 11, s = gm & 2047;
          const int h = gn >> 6, hd = gn & 63;
          uint64_t addr;
          if (mode == 1) {
            addr = ((uint64_t)(b * 16 + h) * 2048 + s) * 64 + hd;
          } else {
            // key-permute within each 32-block: p = qd*8 + knt*4 + r
            const int sp2 = (s & ~31) |
                            ((s & 3) | (((s >> 2) & 3) << 3) | (((s >> 4) & 1) << 2));
            addr = ((uint64_t)(b * 16 + h) * 64 + hd) * 2048 + sp2;
          }
          op[addr] = (bf16)v;
        }
      }
    }
  }
}

// ---------------------------------------------------------------------------
// Flash attention v11: 8 waves (512 threads), wave split 4x2 (wq x wk),
// single-buffered 2-barrier loop, P register-resident (v10), V key-permuted
// in memory so the PV B-frag is a single b128 read.
// 1D grid 512 blocks, XCD-swizzled: xcd=id&7, k=id>>3, bh=xcd*4+(k>>4),
// qt=k&15, q0=qt*128.  Wave (wq in [0,4), wk in {0,1}): queries
// q0+wq*32+mt*16+cl (mt=0..1), keys wk*32+[0,32) of each 64-key tile.
// Per mt: s_knt = mfma(K_half,Q) (K=64 over d) -> exp2 -> pk[knt] bf16x4;
// PV A-frag = {pk[0],pk[1]}; B-frag = b128 of permuted V at chunk
// (wk*4+quad)^(cl&7) (same conflict-benign pattern as the K reads).
// Epilogue: cross-wave (wk) O+l reduction; Obuf aliases the K/V region.
// ---------------------------------------------------------------------------
__global__ __launch_bounds__(512, 4)
void attn_kernel(const bf16* __restrict__ Qw, const bf16* __restrict__ Kw,
                 const bf16* __restrict__ Vtw, bf16* __restrict__ Ctx) {
  // loop: [0,8K) Ks | [8K,16K) Vs.  epilogue: Obuf[4][2048] fp32 on [0,32K).
  __shared__ char smem[32768];
  __shared__ float Lbuf[256];           // [wq*2+wk][32 queries]

  bf16* Ks = (bf16*)smem;               // [key][d], chunk c^(key&7)
  bf16* Vs = (bf16*)(smem + 8192);      // [hd][key-permuted], chunk c^(hd&7)
  float* Ob = (float*)smem;             // epilogue alias

  const int t = threadIdx.x, lane = t & 63, w = t >> 6;
  const int cl = lane & 15, quad = lane >> 4;
  const int wq = w >> 1, wk = w & 1;

  const int id = blockIdx.x;
  const int xcd = id & 7, kk = id >> 3;
  const int bh = xcd * 4 + (kk >> 4);
  const int qt = kk & 15;
  const int b = bh >> 4, h = bh & 15;
  const int q0 = qt * 128;

  const bf16* Qh = Qw + (uint64_t)bh * 2048 * 64;
  const bf16* Kh = Kw + (uint64_t)bh * 2048 * 64;
  const bf16* Vh = Vtw + (uint64_t)bh * 64 * 2048;

  // Q B-fragments: B[k=h*32+quad*8+j][n=cl], queries q0+wq*32+mt*16+cl
  bf16x8 qf[2][2];
#pragma unroll
  for (int mt = 0; mt < 2; mt++) {
    const int r = q0 + wq * 32 + mt * 16 + cl;
    qf[mt][0] = *(const bf16x8*)&Qh[(uint64_t)r * 64 + quad * 8];
    qf[mt][1] = *(const bf16x8*)&Qh[(uint64_t)r * 64 + 32 + quad * 8];
  }

  f32x4 zero = {0.f, 0.f, 0.f, 0.f};
  f32x4 o_acc[2][4];
  float lsum[2] = {0.f, 0.f};
#pragma unroll
  for (int mt = 0; mt < 2; mt++)
#pragma unroll
    for (int nt = 0; nt < 4; nt++) o_acc[mt][nt] = zero;

  const int srow = t >> 3;                         // 0..63
  const int gcol_sw = ((t & 7) ^ (srow & 7)) * 8;  // swizzled source col
  const int lcV = wk * 4 + quad;                   // V b128 logical chunk

  for (int k0 = 0; k0 < 2048; k0 += 64) {
    __syncthreads();
    gl_lds16(Kh + (uint64_t)(k0 + srow) * 64 + gcol_sw, (char*)Ks + t * 16);
    gl_lds16(Vh + (uint64_t)srow * 2048 + k0 + gcol_sw, (char*)Vs + t * 16);
    __syncthreads();   // tiles resident

    // K A-frags for this wave's 32-key half
    bf16x8 kf[2][2];
#pragma unroll
    for (int knt = 0; knt < 2; knt++) {
      const int krow = wk * 32 + knt * 16 + cl;
#pragma unroll
      for (int hh = 0; hh < 2; hh++)
        kf[knt][hh] = *(const bf16x8*)&Ks[krow * 64 +
                                          (((hh * 4 + quad) ^ (cl & 7)) << 3)];
    }
    // V B-frags: single b128 of permuted V (contraction units {2q,2q+1})
    bf16x8 vf[4];
#pragma unroll
    for (int nt = 0; nt < 4; nt++)
      vf[nt] = *(const bf16x8*)&Vs[(nt * 16 + cl) * 64 +
                                   ((lcV ^ (cl & 7)) << 3)];

    // Per mt: S^T (log2 units) -> exp2 -> pk (registers) -> PV
#pragma unroll
    for (int mt = 0; mt < 2; mt++) {
      bf16x4 pk[2];
#pragma unroll
      for (int knt = 0; knt < 2; knt++) {
        f32x4 s = __builtin_amdgcn_mfma_f32_16x16x32_bf16(kf[knt][0], qf[mt][0],
                                                          zero, 0, 0, 0);
        s = __builtin_amdgcn_mfma_f32_16x16x32_bf16(kf[knt][1], qf[mt][1], s, 0, 0, 0);
        float ls = 0.f;
#pragma unroll
        for (int r = 0; r < 4; r++) {
          const float p = __builtin_amdgcn_exp2f(s[r]);
          ls += p;
          pk[knt][r] = (bf16)p;
        }
        lsum[mt] += ls;
      }
      union { bf16x4 h[2]; bf16x8 v; } pf;
      pf.h[0] = pk[0];   // half0 keys quad*4+0..3  (contraction j=0..3)
      pf.h[1] = pk[1];   // half1 keys quad*4+0..3  (contraction j=4..7)
#pragma unroll
      for (int nt = 0; nt < 4; nt++)
        o_acc[mt][nt] = __builtin_amdgcn_mfma_f32_16x16x32_bf16(pf.v, vf[nt],
                                                                o_acc[mt][nt],
                                                                0, 0, 0);
    }
  }

  // ---- epilogue: per-wave l reduce, then cross-wk O/l combine ----
#pragma unroll
  for (int mt = 0; mt < 2; mt++) {
    float l = lsum[mt];
    l += __shfl_xor(l, 16);
    l += __shfl_xor(l, 32);
    if (lane < 16) Lbuf[w * 32 + mt * 16 + lane] = l;
  }
  __syncthreads();            // loop reads done -> smem reusable for Obuf
  if (wk == 1) {
#pragma unroll
    for (int mt = 0; mt < 2; mt++)
#pragma unroll
      for (int nt = 0; nt < 4; nt++)
        *(f32x4*)&Ob[wq * 2048 + (mt * 4 + nt) * 256 + lane * 4] = o_acc[mt][nt];
  }
  __syncthreads();
  if (wk == 0) {
#pragma unroll
    for (int mt = 0; mt < 2; mt++) {
      float linv[4];
#pragma unroll
      for (int r = 0; r < 4; r++) {
        const int ql = mt * 16 + quad * 4 + r;
        linv[r] = 1.0f / (Lbuf[(wq * 2) * 32 + ql] + Lbuf[(wq * 2 + 1) * 32 + ql]);
      }
#pragma unroll
      for (int nt = 0; nt < 4; nt++) {
        f32x4 other = *(const f32x4*)&Ob[wq * 2048 + (mt * 4 + nt) * 256 + lane * 4];
#pragma unroll
        for (int r = 0; r < 4; r++) {
          const int q = q0 + wq * 32 + mt * 16 + quad * 4 + r;
          const int hd = nt * 16 + cl;
          Ctx[(uint64_t)(b * 2048 + q) * 1024 + h * 64 + hd] =
              (bf16)((o_acc[mt][nt][r] + other[r]) * linv[r]);
        }
      }
    }
  }
}

// ---------------------------------------------------------------------------
extern "C" void kernel_launch(void* const* d_in, const int* in_sizes, int n_in,
                              void* d_out, int out_size, void* d_ws, size_t ws_size,
                              hipStream_t stream) {
  const float* x  = (const float*)d_in[0];
  const float* Wq = (const float*)d_in[1];
  const float* Wk = (const float*)d_in[2];
  const float* Wv = (const float*)d_in[3];
  const float* Wo = (const float*)d_in[4];
  const float* qs = (const float*)d_in[5];
  const float* ks = (const float*)d_in[6];
  const float* vs = (const float*)d_in[7];
  const float* os = (const float*)d_in[8];
  float* out = (float*)d_out;

  const size_t M4 = 4194304, M1 = 1048576;

  if (ws_size >= (size_t)40 * 1024 * 1024) {
    bf16* xb = (bf16*)d_ws;        // 4M bf16; reused as cw after QKV
    bf16* wb = xb + M4;            // wq|wk|wv|wo
    bf16* qw = wb + M4;
    bf16* kw = qw + M4;
    bf16* vw = kw + M4;
    bf16* cw = xb;

    cvt_kernel<<<dim3(512, 8), 256, 0, stream>>>(x, Wq, Wk, Wv, Wo, xb, wb);
    gemm_kernel<bf16, bf16, 128><<<dim3(32, 24), 256, 0, stream>>>(
        xb, wb, wb + M1, wb + 2 * M1, qs, ks, vs, qw, kw, vw, nullptr, 1);
    attn_kernel<<<512, 512, 0, stream>>>(qw, kw, vw, cw);
    gemm_kernel<bf16, bf16, 64><<<dim3(32, 16), 256, 0, stream>>>(
        cw, wb + 3 * M1, nullptr, nullptr, os, nullptr, nullptr,
        nullptr, nullptr, nullptr, out, 0);
  } else {
    bf16* qw = (bf16*)d_ws;
    bf16* kw = qw + M4;
    bf16* vw = kw + M4;
    bf16* cw = vw + M4;
    gemm_kernel<float, float, 128><<<dim3(32, 24), 256, 0, stream>>>(
        x, Wq, Wk, Wv, qs, ks, vs, qw, kw, vw, nullptr, 1);
    attn_kernel<<<512, 512, 0, stream>>>(qw, kw, vw, cw);
    gemm_kernel<bf16, float, 64><<<dim3(32, 16), 256, 0, stream>>>(
        cw, Wo, nullptr, nullptr, os, nullptr, nullptr,
        nullptr, nullptr, nullptr, out, 0);
  }
}

// Round 9
// 184.394 us; speedup vs baseline: 1.4214x; 1.0036x over previous
//
#include <hip/hip_runtime.h>
#include <hip/hip_bf16.h>
#include <stdint.h>

// B=2, S=2048, D=1024, H=16, Hd=64.  Inputs/outputs FP32; internal bf16 MFMA.
// R19 = R18 (attn v11 register-P + V key-permute; 185.1us) + mode-1 GEMM
// epilogue rewrite: Q/K outputs ([B,H,S,64]; each wave's 64x64 tile = one
// head's CONTIGUOUS 8KB region) now go through a per-wave LDS transpose
// (private 4KB slice of the dead As/Bs region, 72-col pad) and store as 8
// coalesced bf16x8 per thread instead of 64 scalar 2B stores.  Targets the
// measured 1.8x WRITE amplification (42.9 vs 24MB) and the 610-vs-900 TF
// deficit of the QKV gemm.  Mode 2 (V, permuted) and mode 0 unchanged.

typedef __bf16 bf16;
typedef __attribute__((ext_vector_type(8))) __bf16 bf16x8;
typedef __attribute__((ext_vector_type(4))) __bf16 bf16x4;
typedef __attribute__((ext_vector_type(4))) float f32x4;

#define DEVI __device__ __forceinline__

DEVI void gl_lds16(const void* g, void* l) {
  __builtin_amdgcn_global_load_lds(
      (const __attribute__((address_space(1))) void*)g,
      (__attribute__((address_space(3))) void*)l, 16, 0, 0);
}

DEVI bf16x8 load8(const bf16* p) { return *(const bf16x8*)p; }
DEVI bf16x8 load8(const float* p) {
  f32x4 a = *(const f32x4*)p;
  f32x4 b = *(const f32x4*)(p + 4);
  bf16x8 r;
  r[0] = (bf16)a[0]; r[1] = (bf16)a[1]; r[2] = (bf16)a[2]; r[3] = (bf16)a[3];
  r[4] = (bf16)b[0]; r[5] = (bf16)b[1]; r[6] = (bf16)b[2]; r[7] = (bf16)b[3];
  return r;
}

// ---------------------------------------------------------------------------
// fp32 -> bf16 bulk convert.  grid (512, 8): y<4 -> W[y], y>=4 -> x quarter.
// ---------------------------------------------------------------------------
__global__ __launch_bounds__(256)
void cvt_kernel(const float* __restrict__ x,
                const float* __restrict__ w0, const float* __restrict__ w1,
                const float* __restrict__ w2, const float* __restrict__ w3,
                bf16* __restrict__ xb, bf16* __restrict__ wb) {
  const int y = blockIdx.y;
  const float* src;
  bf16* dst;
  if (y < 4) {
    src = (y == 0) ? w0 : (y == 1) ? w1 : (y == 2) ? w2 : w3;
    dst = wb + (size_t)y * 1048576;
  } else {
    src = x + (size_t)(y - 4) * 1048576;
    dst = xb + (size_t)(y - 4) * 1048576;
  }
  const int i = (blockIdx.x * 256 + threadIdx.x) * 8;
  *(bf16x8*)(dst + i) = load8(src + i);
}

// ---------------------------------------------------------------------------
// GEMM: C[m,n] = (sum_k X[m,k]*W[n,k]) * scale[n] [*emul].
// bf16 operands stage via global_load_lds (src-swizzled); fp32 manual.
// three=1 (NTILE=128): 8 n-tiles per W; Q/K -> [B,H,S,64] via LDS-transpose
//   coalesced epilogue (Q gets emul=0.125*log2e), V -> transposed [B,H,64,S]
//   with keys PERMUTED within each 32-block (attn PV contraction order).
// three=0 (NTILE=64): plain fp32 row-major out.
// ---------------------------------------------------------------------------
template <typename XT, typename WT, int NTILE>
__global__ __launch_bounds__(256, 2)
void gemm_kernel(const XT* __restrict__ X,
                 const WT* __restrict__ W0, const WT* __restrict__ W1,
                 const WT* __restrict__ W2,
                 const float* __restrict__ s0, const float* __restrict__ s1,
                 const float* __restrict__ s2,
                 bf16* __restrict__ o0, bf16* __restrict__ o1,
                 bf16* __restrict__ o2, float* __restrict__ ofp, int three) {
  constexpr int NF = NTILE / 32;
  constexpr bool ASYNC_A = (sizeof(XT) == 2);
  constexpr bool ASYNC_B = (sizeof(WT) == 2);
  __shared__ bf16 As[128 * 32];
  __shared__ bf16 Bs[NTILE * 32];

  const int t = threadIdx.x;
  const int lane = t & 63;
  const int w = t >> 6;
  const int wm = w >> 1, wn = w & 1;
  const int m0 = blockIdx.x * 128;
  const int cl = lane & 15, quad = lane >> 4;

  const WT* Wp; const float* sp; bf16* op; int mode, n0; float emul = 1.f;
  if (three) {
    int which = blockIdx.y >> 3;
    n0 = (blockIdx.y & 7) * 128;
    if (which == 0)      { Wp = W0; sp = s0; op = o0; mode = 1; emul = 0.18033688f; }
    else if (which == 1) { Wp = W1; sp = s1; op = o1; mode = 1; }
    else                 { Wp = W2; sp = s2; op = o2; mode = 2; }
  } else {
    n0 = blockIdx.y * NTILE; Wp = W0; sp = s0; op = o0; mode = 0;
  }

  f32x4 zero = {0.f, 0.f, 0.f, 0.f};
  f32x4 acc[4][NF];
#pragma unroll
  for (int i = 0; i < 4; i++)
#pragma unroll
    for (int j = 0; j < NF; j++) acc[i][j] = zero;

  const int srow = t >> 2;
  const int gcol_sw = ((t & 3) ^ (srow & 3)) * 8;
  const int gcol = (t & 3) * 8;
  const int sphys = (((t & 3) ^ (srow & 3)) << 3);

  for (int k0 = 0; k0 < 1024; k0 += 32) {
    bf16x8 a0, a1, b0, b1;
    if constexpr (!ASYNC_A) {
      a0 = load8(&X[(uint64_t)(m0 + srow) * 1024 + k0 + gcol]);
      a1 = load8(&X[(uint64_t)(m0 + 64 + srow) * 1024 + k0 + gcol]);
    }
    if constexpr (!ASYNC_B) {
      b0 = load8(&Wp[(uint64_t)(n0 + srow) * 1024 + k0 + gcol]);
      if constexpr (NTILE == 128)
        b1 = load8(&Wp[(uint64_t)(n0 + 64 + srow) * 1024 + k0 + gcol]);
    }
    __syncthreads();
    if constexpr (ASYNC_A) {
      gl_lds16(X + (uint64_t)(m0 + srow) * 1024 + k0 + gcol_sw, (char*)As + t * 16);
      gl_lds16(X + (uint64_t)(m0 + 64 + srow) * 1024 + k0 + gcol_sw,
               (char*)As + 4096 + t * 16);
    } else {
      *(bf16x8*)&As[srow * 32 + sphys] = a0;
      *(bf16x8*)&As[(64 + srow) * 32 + sphys] = a1;
    }
    if constexpr (ASYNC_B) {
      gl_lds16(Wp + (uint64_t)(n0 + srow) * 1024 + k0 + gcol_sw, (char*)Bs + t * 16);
      if constexpr (NTILE == 128)
        gl_lds16(Wp + (uint64_t)(n0 + 64 + srow) * 1024 + k0 + gcol_sw,
                 (char*)Bs + 4096 + t * 16);
    } else {
      *(bf16x8*)&Bs[srow * 32 + sphys] = b0;
      if constexpr (NTILE == 128)
        *(bf16x8*)&Bs[(64 + srow) * 32 + sphys] = b1;
    }
    __syncthreads();

    bf16x8 af[4], bfr[NF];
#pragma unroll
    for (int mt = 0; mt < 4; mt++) {
      const int row = wm * 64 + mt * 16 + cl;
      af[mt] = *(const bf16x8*)&As[row * 32 + ((quad ^ (cl & 3)) << 3)];
    }
#pragma unroll
    for (int nt = 0; nt < NF; nt++) {
      const int row = wn * (NF * 16) + nt * 16 + cl;
      bfr[nt] = *(const bf16x8*)&Bs[row * 32 + ((quad ^ (cl & 3)) << 3)];
    }
#pragma unroll
    for (int mt = 0; mt < 4; mt++)
#pragma unroll
      for (int nt = 0; nt < NF; nt++)
        acc[mt][nt] = __builtin_amdgcn_mfma_f32_16x16x32_bf16(af[mt], bfr[nt],
                                                              acc[mt][nt], 0, 0, 0);
  }

  bool handled = false;
  if constexpr (NTILE == 128) {
    if (mode == 1) {
      handled = true;
      // ---- coalesced LDS-transpose epilogue (Q/K) ----
      // Wave tile = one head's contiguous [64 s][64 hd] region.
      __syncthreads();   // all waves done reading As/Bs
      bf16* slice = (w < 2) ? (bf16*)((char*)As + w * 4096)
                            : (bf16*)((char*)Bs + (w - 2) * 4096);
      const int h = (n0 >> 6) + wn;
      float scv[4];
#pragma unroll
      for (int nt = 0; nt < 4; nt++)
        scv[nt] = sp[n0 + wn * 64 + nt * 16 + cl] * emul;
#pragma unroll
      for (int mt = 0; mt < 4; mt++) {
        // stage 16 s x 64 hd (+8 pad -> 72-col rows, 144B, b128-aligned)
#pragma unroll
        for (int nt = 0; nt < 4; nt++)
#pragma unroll
          for (int r = 0; r < 4; r++)
            slice[(quad * 4 + r) * 72 + nt * 16 + cl] =
                (bf16)(acc[mt][nt][r] * scv[nt]);
        // readback b128 + coalesced store (wave covers 16 rows x 128B)
#pragma unroll
        for (int rr = 0; rr < 2; rr++) {
          const int sr = rr * 8 + (lane >> 3);
          const int hdc = (lane & 7) * 8;
          bf16x8 v = *(const bf16x8*)&slice[sr * 72 + hdc];
          const int gm = m0 + wm * 64 + mt * 16 + sr;
          const int bb = gm >> 11, ss = gm & 2047;
          *(bf16x8*)&op[((uint64_t)(bb * 16 + h) * 2048 + ss) * 64 + hdc] = v;
        }
      }
    }
  }

  if (!handled) {
#pragma unroll
    for (int nt = 0; nt < NF; nt++) {
      const int gn = n0 + wn * (NF * 16) + nt * 16 + cl;
      const float sc = sp[gn] * emul;
#pragma unroll
      for (int mt = 0; mt < 4; mt++) {
        const int gmb = m0 + wm * 64 + mt * 16 + quad * 4;
#pragma unroll
        for (int r = 0; r < 4; r++) {
          const int gm = gmb + r;
          const float v = acc[mt][nt][r] * sc;
          if (mode == 0) {
            ofp[(uint64_t)gm * 1024 + gn] = v;
          } else {
            const int b = gm >> 11, s = gm & 2047;
            const int h = gn >> 6, hd = gn & 63;
            // mode 2: key-permute within each 32-block: p = qd*8 + knt*4 + r
            const int sp2 = (s & ~31) |
                            ((s & 3) | (((s >> 2) & 3) << 3) | (((s >> 4) & 1) << 2));
            uint64_t addr = ((uint64_t)(b * 16 + h) * 64 + hd) * 2048 + sp2;
            op[addr] = (bf16)v;
          }
        }
      }
    }
  }
}

// ---------------------------------------------------------------------------
// Flash attention v11: 8 waves (512 threads), wave split 4x2 (wq x wk),
// single-buffered 2-barrier loop, P register-resident, V key-permuted in
// memory so the PV B-frag is a single b128 read.
// 1D grid 512 blocks, XCD-swizzled: xcd=id&7, k=id>>3, bh=xcd*4+(k>>4),
// qt=k&15, q0=qt*128.  Wave (wq in [0,4), wk in {0,1}): queries
// q0+wq*32+mt*16+cl (mt=0..1), keys wk*32+[0,32) of each 64-key tile.
// Per mt: s_knt = mfma(K_half,Q) (K=64 over d) -> exp2 -> pk[knt] bf16x4;
// PV A-frag = {pk[0],pk[1]}; B-frag = b128 of permuted V at chunk
// (wk*4+quad)^(cl&7) (same conflict-benign pattern as the K reads).
// Epilogue: cross-wave (wk) O+l reduction; Obuf aliases the K/V region.
// ---------------------------------------------------------------------------
__global__ __launch_bounds__(512, 4)
void attn_kernel(const bf16* __restrict__ Qw, const bf16* __restrict__ Kw,
                 const bf16* __restrict__ Vtw, bf16* __restrict__ Ctx) {
  // loop: [0,8K) Ks | [8K,16K) Vs.  epilogue: Obuf[4][2048] fp32 on [0,32K).
  __shared__ char smem[32768];
  __shared__ float Lbuf[256];           // [wq*2+wk][32 queries]

  bf16* Ks = (bf16*)smem;               // [key][d], chunk c^(key&7)
  bf16* Vs = (bf16*)(smem + 8192);      // [hd][key-permuted], chunk c^(hd&7)
  float* Ob = (float*)smem;             // epilogue alias

  const int t = threadIdx.x, lane = t & 63, w = t >> 6;
  const int cl = lane & 15, quad = lane >> 4;
  const int wq = w >> 1, wk = w & 1;

  const int id = blockIdx.x;
  const int xcd = id & 7, kk = id >> 3;
  const int bh = xcd * 4 + (kk >> 4);
  const int qt = kk & 15;
  const int b = bh >> 4, h = bh & 15;
  const int q0 = qt * 128;

  const bf16* Qh = Qw + (uint64_t)bh * 2048 * 64;
  const bf16* Kh = Kw + (uint64_t)bh * 2048 * 64;
  const bf16* Vh = Vtw + (uint64_t)bh * 64 * 2048;

  // Q B-fragments: B[k=h*32+quad*8+j][n=cl], queries q0+wq*32+mt*16+cl
  bf16x8 qf[2][2];
#pragma unroll
  for (int mt = 0; mt < 2; mt++) {
    const int r = q0 + wq * 32 + mt * 16 + cl;
    qf[mt][0] = *(const bf16x8*)&Qh[(uint64_t)r * 64 + quad * 8];
    qf[mt][1] = *(const bf16x8*)&Qh[(uint64_t)r * 64 + 32 + quad * 8];
  }

  f32x4 zero = {0.f, 0.f, 0.f, 0.f};
  f32x4 o_acc[2][4];
  float lsum[2] = {0.f, 0.f};
#pragma unroll
  for (int mt = 0; mt < 2; mt++)
#pragma unroll
    for (int nt = 0; nt < 4; nt++) o_acc[mt][nt] = zero;

  const int srow = t >> 3;                         // 0..63
  const int gcol_sw = ((t & 7) ^ (srow & 7)) * 8;  // swizzled source col
  const int lcV = wk * 4 + quad;                   // V b128 logical chunk

  for (int k0 = 0; k0 < 2048; k0 += 64) {
    __syncthreads();
    gl_lds16(Kh + (uint64_t)(k0 + srow) * 64 + gcol_sw, (char*)Ks + t * 16);
    gl_lds16(Vh + (uint64_t)srow * 2048 + k0 + gcol_sw, (char*)Vs + t * 16);
    __syncthreads();   // tiles resident

    // K A-frags for this wave's 32-key half
    bf16x8 kf[2][2];
#pragma unroll
    for (int knt = 0; knt < 2; knt++) {
      const int krow = wk * 32 + knt * 16 + cl;
#pragma unroll
      for (int hh = 0; hh < 2; hh++)
        kf[knt][hh] = *(const bf16x8*)&Ks[krow * 64 +
                                          (((hh * 4 + quad) ^ (cl & 7)) << 3)];
    }
    // V B-frags: single b128 of permuted V (contraction units {2q,2q+1})
    bf16x8 vf[4];
#pragma unroll
    for (int nt = 0; nt < 4; nt++)
      vf[nt] = *(const bf16x8*)&Vs[(nt * 16 + cl) * 64 +
                                   ((lcV ^ (cl & 7)) << 3)];

    // Per mt: S^T (log2 units) -> exp2 -> pk (registers) -> PV
#pragma unroll
    for (int mt = 0; mt < 2; mt++) {
      bf16x4 pk[2];
#pragma unroll
      for (int knt = 0; knt < 2; knt++) {
        f32x4 s = __builtin_amdgcn_mfma_f32_16x16x32_bf16(kf[knt][0], qf[mt][0],
                                                          zero, 0, 0, 0);
        s = __builtin_amdgcn_mfma_f32_16x16x32_bf16(kf[knt][1], qf[mt][1], s, 0, 0, 0);
        float ls = 0.f;
#pragma unroll
        for (int r = 0; r < 4; r++) {
          const float p = __builtin_amdgcn_exp2f(s[r]);
          ls += p;
          pk[knt][r] = (bf16)p;
        }
        lsum[mt] += ls;
      }
      union { bf16x4 h[2]; bf16x8 v; } pf;
      pf.h[0] = pk[0];   // half0 keys quad*4+0..3  (contraction j=0..3)
      pf.h[1] = pk[1];   // half1 keys quad*4+0..3  (contraction j=4..7)
#pragma unroll
      for (int nt = 0; nt < 4; nt++)
        o_acc[mt][nt] = __builtin_amdgcn_mfma_f32_16x16x32_bf16(pf.v, vf[nt],
                                                                o_acc[mt][nt],
                                                                0, 0, 0);
    }
  }

  // ---- epilogue: per-wave l reduce, then cross-wk O/l combine ----
#pragma unroll
  for (int mt = 0; mt < 2; mt++) {
    float l = lsum[mt];
    l += __shfl_xor(l, 16);
    l += __shfl_xor(l, 32);
    if (lane < 16) Lbuf[w * 32 + mt * 16 + lane] = l;
  }
  __syncthreads();            // loop reads done -> smem reusable for Obuf
  if (wk == 1) {
#pragma unroll
    for (int mt = 0; mt < 2; mt++)
#pragma unroll
      for (int nt = 0; nt < 4; nt++)
        *(f32x4*)&Ob[wq * 2048 + (mt * 4 + nt) * 256 + lane * 4] = o_acc[mt][nt];
  }
  __syncthreads();
  if (wk == 0) {
#pragma unroll
    for (int mt = 0; mt < 2; mt++) {
      float linv[4];
#pragma unroll
      for (int r = 0; r < 4; r++) {
        const int ql = mt * 16 + quad * 4 + r;
        linv[r] = 1.0f / (Lbuf[(wq * 2) * 32 + ql] + Lbuf[(wq * 2 + 1) * 32 + ql]);
      }
#pragma unroll
      for (int nt = 0; nt < 4; nt++) {
        f32x4 other = *(const f32x4*)&Ob[wq * 2048 + (mt * 4 + nt) * 256 + lane * 4];
#pragma unroll
        for (int r = 0; r < 4; r++) {
          const int q = q0 + wq * 32 + mt * 16 + quad * 4 + r;
          const int hd = nt * 16 + cl;
          Ctx[(uint64_t)(b * 2048 + q) * 1024 + h * 64 + hd] =
              (bf16)((o_acc[mt][nt][r] + other[r]) * linv[r]);
        }
      }
    }
  }
}

// ---------------------------------------------------------------------------
extern "C" void kernel_launch(void* const* d_in, const int* in_sizes, int n_in,
                              void* d_out, int out_size, void* d_ws, size_t ws_size,
                              hipStream_t stream) {
  const float* x  = (const float*)d_in[0];
  const float* Wq = (const float*)d_in[1];
  const float* Wk = (const float*)d_in[2];
  const float* Wv = (const float*)d_in[3];
  const float* Wo = (const float*)d_in[4];
  const float* qs = (const float*)d_in[5];
  const float* ks = (const float*)d_in[6];
  const float* vs = (const float*)d_in[7];
  const float* os = (const float*)d_in[8];
  float* out = (float*)d_out;

  const size_t M4 = 4194304, M1 = 1048576;

  if (ws_size >= (size_t)40 * 1024 * 1024) {
    bf16* xb = (bf16*)d_ws;        // 4M bf16; reused as cw after QKV
    bf16* wb = xb + M4;            // wq|wk|wv|wo
    bf16* qw = wb + M4;
    bf16* kw = qw + M4;
    bf16* vw = kw + M4;
    bf16* cw = xb;

    cvt_kernel<<<dim3(512, 8), 256, 0, stream>>>(x, Wq, Wk, Wv, Wo, xb, wb);
    gemm_kernel<bf16, bf16, 128><<<dim3(32, 24), 256, 0, stream>>>(
        xb, wb, wb + M1, wb + 2 * M1, qs, ks, vs, qw, kw, vw, nullptr, 1);
    attn_kernel<<<512, 512, 0, stream>>>(qw, kw, vw, cw);
    gemm_kernel<bf16, bf16, 64><<<dim3(32, 16), 256, 0, stream>>>(
        cw, wb + 3 * M1, nullptr, nullptr, os, nullptr, nullptr,
        nullptr, nullptr, nullptr, out, 0);
  } else {
    bf16* qw = (bf16*)d_ws;
    bf16* kw = qw + M4;
    bf16* vw = kw + M4;
    bf16* cw = vw + M4;
    gemm_kernel<float, float, 128><<<dim3(32, 24), 256, 0, stream>>>(
        x, Wq, Wk, Wv, qs, ks, vs, qw, kw, vw, nullptr, 1);
    attn_kernel<<<512, 512, 0, stream>>>(qw, kw, vw, cw);
    gemm_kernel<bf16, float, 64><<<dim3(32, 16), 256, 0, stream>>>(
        cw, Wo, nullptr, nullptr, os, nullptr, nullptr,
        nullptr, nullptr, nullptr, out, 0);
  }
}

// Round 10
// 182.638 us; speedup vs baseline: 1.4350x; 1.0096x over previous
//
#include <hip/hip_runtime.h>
#include <hip/hip_bf16.h>
#include <stdint.h>

// B=2, S=2048, D=1024, H=16, Hd=64.  Inputs/outputs FP32; internal bf16 MFMA.
// R20 = R19 (184.4us) + two edits:
// (1) attn: softmax denominator via MFMA ones-column -- l_acc[mt] =
//     mfma(pf, ones) replaces 16 fp32 adds/tile + the epilogue shuffle
//     reduce; l now sums the SAME bf16 P as the numerator (self-consistent).
// (2) gemm2 (mode 0): coalesced epilogue -- per-wave 2KB slice of dead As,
//     col rotated by 4*row (mod 32, f32x4-preserving), f32x4 readback and
//     full-128B-line stores instead of 64 scalar 4B stores.  Bit-exact.

typedef __bf16 bf16;
typedef __attribute__((ext_vector_type(8))) __bf16 bf16x8;
typedef __attribute__((ext_vector_type(4))) __bf16 bf16x4;
typedef __attribute__((ext_vector_type(4))) float f32x4;

#define DEVI __device__ __forceinline__

DEVI void gl_lds16(const void* g, void* l) {
  __builtin_amdgcn_global_load_lds(
      (const __attribute__((address_space(1))) void*)g,
      (__attribute__((address_space(3))) void*)l, 16, 0, 0);
}

DEVI bf16x8 load8(const bf16* p) { return *(const bf16x8*)p; }
DEVI bf16x8 load8(const float* p) {
  f32x4 a = *(const f32x4*)p;
  f32x4 b = *(const f32x4*)(p + 4);
  bf16x8 r;
  r[0] = (bf16)a[0]; r[1] = (bf16)a[1]; r[2] = (bf16)a[2]; r[3] = (bf16)a[3];
  r[4] = (bf16)b[0]; r[5] = (bf16)b[1]; r[6] = (bf16)b[2]; r[7] = (bf16)b[3];
  return r;
}

// ---------------------------------------------------------------------------
// fp32 -> bf16 bulk convert.  grid (512, 8): y<4 -> W[y], y>=4 -> x quarter.
// ---------------------------------------------------------------------------
__global__ __launch_bounds__(256)
void cvt_kernel(const float* __restrict__ x,
                const float* __restrict__ w0, const float* __restrict__ w1,
                const float* __restrict__ w2, const float* __restrict__ w3,
                bf16* __restrict__ xb, bf16* __restrict__ wb) {
  const int y = blockIdx.y;
  const float* src;
  bf16* dst;
  if (y < 4) {
    src = (y == 0) ? w0 : (y == 1) ? w1 : (y == 2) ? w2 : w3;
    dst = wb + (size_t)y * 1048576;
  } else {
    src = x + (size_t)(y - 4) * 1048576;
    dst = xb + (size_t)(y - 4) * 1048576;
  }
  const int i = (blockIdx.x * 256 + threadIdx.x) * 8;
  *(bf16x8*)(dst + i) = load8(src + i);
}

// ---------------------------------------------------------------------------
// GEMM: C[m,n] = (sum_k X[m,k]*W[n,k]) * scale[n] [*emul].
// bf16 operands stage via global_load_lds (src-swizzled); fp32 manual.
// three=1 (NTILE=128): 8 n-tiles per W; Q/K -> [B,H,S,64] via LDS-transpose
//   coalesced epilogue (Q gets emul=0.125*log2e), V -> transposed [B,H,64,S]
//   with keys PERMUTED within each 32-block (attn PV contraction order).
// three=0 (NTILE=64): fp32 row-major out via coalesced LDS epilogue.
// ---------------------------------------------------------------------------
template <typename XT, typename WT, int NTILE>
__global__ __launch_bounds__(256, 2)
void gemm_kernel(const XT* __restrict__ X,
                 const WT* __restrict__ W0, const WT* __restrict__ W1,
                 const WT* __restrict__ W2,
                 const float* __restrict__ s0, const float* __restrict__ s1,
                 const float* __restrict__ s2,
                 bf16* __restrict__ o0, bf16* __restrict__ o1,
                 bf16* __restrict__ o2, float* __restrict__ ofp, int three) {
  constexpr int NF = NTILE / 32;
  constexpr bool ASYNC_A = (sizeof(XT) == 2);
  constexpr bool ASYNC_B = (sizeof(WT) == 2);
  __shared__ bf16 As[128 * 32];
  __shared__ bf16 Bs[NTILE * 32];

  const int t = threadIdx.x;
  const int lane = t & 63;
  const int w = t >> 6;
  const int wm = w >> 1, wn = w & 1;
  const int m0 = blockIdx.x * 128;
  const int cl = lane & 15, quad = lane >> 4;

  const WT* Wp; const float* sp; bf16* op; int mode, n0; float emul = 1.f;
  if (three) {
    int which = blockIdx.y >> 3;
    n0 = (blockIdx.y & 7) * 128;
    if (which == 0)      { Wp = W0; sp = s0; op = o0; mode = 1; emul = 0.18033688f; }
    else if (which == 1) { Wp = W1; sp = s1; op = o1; mode = 1; }
    else                 { Wp = W2; sp = s2; op = o2; mode = 2; }
  } else {
    n0 = blockIdx.y * NTILE; Wp = W0; sp = s0; op = o0; mode = 0;
  }

  f32x4 zero = {0.f, 0.f, 0.f, 0.f};
  f32x4 acc[4][NF];
#pragma unroll
  for (int i = 0; i < 4; i++)
#pragma unroll
    for (int j = 0; j < NF; j++) acc[i][j] = zero;

  const int srow = t >> 2;
  const int gcol_sw = ((t & 3) ^ (srow & 3)) * 8;
  const int gcol = (t & 3) * 8;
  const int sphys = (((t & 3) ^ (srow & 3)) << 3);

  for (int k0 = 0; k0 < 1024; k0 += 32) {
    bf16x8 a0, a1, b0, b1;
    if constexpr (!ASYNC_A) {
      a0 = load8(&X[(uint64_t)(m0 + srow) * 1024 + k0 + gcol]);
      a1 = load8(&X[(uint64_t)(m0 + 64 + srow) * 1024 + k0 + gcol]);
    }
    if constexpr (!ASYNC_B) {
      b0 = load8(&Wp[(uint64_t)(n0 + srow) * 1024 + k0 + gcol]);
      if constexpr (NTILE == 128)
        b1 = load8(&Wp[(uint64_t)(n0 + 64 + srow) * 1024 + k0 + gcol]);
    }
    __syncthreads();
    if constexpr (ASYNC_A) {
      gl_lds16(X + (uint64_t)(m0 + srow) * 1024 + k0 + gcol_sw, (char*)As + t * 16);
      gl_lds16(X + (uint64_t)(m0 + 64 + srow) * 1024 + k0 + gcol_sw,
               (char*)As + 4096 + t * 16);
    } else {
      *(bf16x8*)&As[srow * 32 + sphys] = a0;
      *(bf16x8*)&As[(64 + srow) * 32 + sphys] = a1;
    }
    if constexpr (ASYNC_B) {
      gl_lds16(Wp + (uint64_t)(n0 + srow) * 1024 + k0 + gcol_sw, (char*)Bs + t * 16);
      if constexpr (NTILE == 128)
        gl_lds16(Wp + (uint64_t)(n0 + 64 + srow) * 1024 + k0 + gcol_sw,
                 (char*)Bs + 4096 + t * 16);
    } else {
      *(bf16x8*)&Bs[srow * 32 + sphys] = b0;
      if constexpr (NTILE == 128)
        *(bf16x8*)&Bs[(64 + srow) * 32 + sphys] = b1;
    }
    __syncthreads();

    bf16x8 af[4], bfr[NF];
#pragma unroll
    for (int mt = 0; mt < 4; mt++) {
      const int row = wm * 64 + mt * 16 + cl;
      af[mt] = *(const bf16x8*)&As[row * 32 + ((quad ^ (cl & 3)) << 3)];
    }
#pragma unroll
    for (int nt = 0; nt < NF; nt++) {
      const int row = wn * (NF * 16) + nt * 16 + cl;
      bfr[nt] = *(const bf16x8*)&Bs[row * 32 + ((quad ^ (cl & 3)) << 3)];
    }
#pragma unroll
    for (int mt = 0; mt < 4; mt++)
#pragma unroll
      for (int nt = 0; nt < NF; nt++)
        acc[mt][nt] = __builtin_amdgcn_mfma_f32_16x16x32_bf16(af[mt], bfr[nt],
                                                              acc[mt][nt], 0, 0, 0);
  }

  bool handled = false;
  if constexpr (NTILE == 128) {
    if (mode == 1) {
      handled = true;
      // ---- coalesced LDS-transpose epilogue (Q/K) ----
      __syncthreads();   // all waves done reading As/Bs
      bf16* slice = (w < 2) ? (bf16*)((char*)As + w * 4096)
                            : (bf16*)((char*)Bs + (w - 2) * 4096);
      const int h = (n0 >> 6) + wn;
      float scv[4];
#pragma unroll
      for (int nt = 0; nt < 4; nt++)
        scv[nt] = sp[n0 + wn * 64 + nt * 16 + cl] * emul;
#pragma unroll
      for (int mt = 0; mt < 4; mt++) {
#pragma unroll
        for (int nt = 0; nt < 4; nt++)
#pragma unroll
          for (int r = 0; r < 4; r++)
            slice[(quad * 4 + r) * 72 + nt * 16 + cl] =
                (bf16)(acc[mt][nt][r] * scv[nt]);
#pragma unroll
        for (int rr = 0; rr < 2; rr++) {
          const int sr = rr * 8 + (lane >> 3);
          const int hdc = (lane & 7) * 8;
          bf16x8 v = *(const bf16x8*)&slice[sr * 72 + hdc];
          const int gm = m0 + wm * 64 + mt * 16 + sr;
          const int bb = gm >> 11, ss = gm & 2047;
          *(bf16x8*)&op[((uint64_t)(bb * 16 + h) * 2048 + ss) * 64 + hdc] = v;
        }
      }
    }
  }
  if constexpr (NTILE == 64) {
    if (mode == 0) {
      handled = true;
      // ---- coalesced fp32 epilogue (Wo output) ----
      // Per-wave 2KB slice of As; 16x32 f32 sub-tile per mt; col rotated by
      // 4*row (mod 32) on both sides (self-inverse, f32x4-preserving).
      __syncthreads();   // all waves done reading As/Bs
      float* slice = (float*)((char*)As + w * 2048);
      float scv[2];
#pragma unroll
      for (int nt = 0; nt < 2; nt++)
        scv[nt] = sp[n0 + wn * 32 + nt * 16 + cl];
#pragma unroll
      for (int mt = 0; mt < 4; mt++) {
#pragma unroll
        for (int nt = 0; nt < 2; nt++)
#pragma unroll
          for (int r = 0; r < 4; r++) {
            const int row = quad * 4 + r;
            const int col = nt * 16 + cl;
            slice[row * 32 + ((col + 4 * row) & 31)] = acc[mt][nt][r] * scv[nt];
          }
#pragma unroll
        for (int p = 0; p < 2; p++) {
          const int sr = p * 8 + (lane >> 3);
          const int c4 = (lane & 7) * 4;
          f32x4 v = *(const f32x4*)&slice[sr * 32 + ((c4 + 4 * sr) & 31)];
          const int gm = m0 + wm * 64 + mt * 16 + sr;
          *(f32x4*)&ofp[(uint64_t)gm * 1024 + n0 + wn * 32 + c4] = v;
        }
      }
    }
  }

  if (!handled) {
#pragma unroll
    for (int nt = 0; nt < NF; nt++) {
      const int gn = n0 + wn * (NF * 16) + nt * 16 + cl;
      const float sc = sp[gn] * emul;
#pragma unroll
      for (int mt = 0; mt < 4; mt++) {
        const int gmb = m0 + wm * 64 + mt * 16 + quad * 4;
#pragma unroll
        for (int r = 0; r < 4; r++) {
          const int gm = gmb + r;
          const float v = acc[mt][nt][r] * sc;
          if (mode == 0) {
            ofp[(uint64_t)gm * 1024 + gn] = v;
          } else {
            const int b = gm >> 11, s = gm & 2047;
            const int h = gn >> 6, hd = gn & 63;
            // mode 2: key-permute within each 32-block: p = qd*8 + knt*4 + r
            const int sp2 = (s & ~31) |
                            ((s & 3) | (((s >> 2) & 3) << 3) | (((s >> 4) & 1) << 2));
            uint64_t addr = ((uint64_t)(b * 16 + h) * 64 + hd) * 2048 + sp2;
            op[addr] = (bf16)v;
          }
        }
      }
    }
  }
}

// ---------------------------------------------------------------------------
// Flash attention v12: 8 waves (512 threads), wave split 4x2 (wq x wk),
// single-buffered 2-barrier loop, P register-resident, V key-permuted in
// memory (single-b128 PV B-frag), softmax denominator via MFMA ones-column:
// l_acc[mt] = mfma(pf, ones) -> lane holds l for its own 4 queries
// (row=quad*4+r), duplicated across cl.  No per-lane adds, no shuffle reduce.
// Epilogue: cross-wave (wk) O+l combine via LDS; Obuf aliases K/V region.
// ---------------------------------------------------------------------------
__global__ __launch_bounds__(512, 4)
void attn_kernel(const bf16* __restrict__ Qw, const bf16* __restrict__ Kw,
                 const bf16* __restrict__ Vtw, bf16* __restrict__ Ctx) {
  // loop: [0,8K) Ks | [8K,16K) Vs.  epilogue: Obuf[4][2048] fp32 on [0,32K).
  __shared__ char smem[32768];
  __shared__ float Lbuf[256];           // [wq*2+wk][32 queries]

  bf16* Ks = (bf16*)smem;               // [key][d], chunk c^(key&7)
  bf16* Vs = (bf16*)(smem + 8192);      // [hd][key-permuted], chunk c^(hd&7)
  float* Ob = (float*)smem;             // epilogue alias

  const int t = threadIdx.x, lane = t & 63, w = t >> 6;
  const int cl = lane & 15, quad = lane >> 4;
  const int wq = w >> 1, wk = w & 1;

  const int id = blockIdx.x;
  const int xcd = id & 7, kk = id >> 3;
  const int bh = xcd * 4 + (kk >> 4);
  const int qt = kk & 15;
  const int b = bh >> 4, h = bh & 15;
  const int q0 = qt * 128;

  const bf16* Qh = Qw + (uint64_t)bh * 2048 * 64;
  const bf16* Kh = Kw + (uint64_t)bh * 2048 * 64;
  const bf16* Vh = Vtw + (uint64_t)bh * 64 * 2048;

  // Q B-fragments: B[k=h*32+quad*8+j][n=cl], queries q0+wq*32+mt*16+cl
  bf16x8 qf[2][2];
#pragma unroll
  for (int mt = 0; mt < 2; mt++) {
    const int r = q0 + wq * 32 + mt * 16 + cl;
    qf[mt][0] = *(const bf16x8*)&Qh[(uint64_t)r * 64 + quad * 8];
    qf[mt][1] = *(const bf16x8*)&Qh[(uint64_t)r * 64 + 32 + quad * 8];
  }

  bf16x8 vones;
#pragma unroll
  for (int j = 0; j < 8; j++) vones[j] = (bf16)1.0f;

  f32x4 zero = {0.f, 0.f, 0.f, 0.f};
  f32x4 o_acc[2][4];
  f32x4 l_acc[2];
#pragma unroll
  for (int mt = 0; mt < 2; mt++) {
    l_acc[mt] = zero;
#pragma unroll
    for (int nt = 0; nt < 4; nt++) o_acc[mt][nt] = zero;
  }

  const int srow = t >> 3;                         // 0..63
  const int gcol_sw = ((t & 7) ^ (srow & 7)) * 8;  // swizzled source col
  const int lcV = wk * 4 + quad;                   // V b128 logical chunk

  for (int k0 = 0; k0 < 2048; k0 += 64) {
    __syncthreads();
    gl_lds16(Kh + (uint64_t)(k0 + srow) * 64 + gcol_sw, (char*)Ks + t * 16);
    gl_lds16(Vh + (uint64_t)srow * 2048 + k0 + gcol_sw, (char*)Vs + t * 16);
    __syncthreads();   // tiles resident

    // K A-frags for this wave's 32-key half
    bf16x8 kf[2][2];
#pragma unroll
    for (int knt = 0; knt < 2; knt++) {
      const int krow = wk * 32 + knt * 16 + cl;
#pragma unroll
      for (int hh = 0; hh < 2; hh++)
        kf[knt][hh] = *(const bf16x8*)&Ks[krow * 64 +
                                          (((hh * 4 + quad) ^ (cl & 7)) << 3)];
    }
    // V B-frags: single b128 of permuted V (contraction units {2q,2q+1})
    bf16x8 vf[4];
#pragma unroll
    for (int nt = 0; nt < 4; nt++)
      vf[nt] = *(const bf16x8*)&Vs[(nt * 16 + cl) * 64 +
                                   ((lcV ^ (cl & 7)) << 3)];

    // Per mt: S^T (log2 units) -> exp2 -> pk (registers) -> PV + l-MFMA
#pragma unroll
    for (int mt = 0; mt < 2; mt++) {
      bf16x4 pk[2];
#pragma unroll
      for (int knt = 0; knt < 2; knt++) {
        f32x4 s = __builtin_amdgcn_mfma_f32_16x16x32_bf16(kf[knt][0], qf[mt][0],
                                                          zero, 0, 0, 0);
        s = __builtin_amdgcn_mfma_f32_16x16x32_bf16(kf[knt][1], qf[mt][1], s, 0, 0, 0);
#pragma unroll
        for (int r = 0; r < 4; r++)
          pk[knt][r] = (bf16)__builtin_amdgcn_exp2f(s[r]);
      }
      union { bf16x4 h[2]; bf16x8 v; } pf;
      pf.h[0] = pk[0];   // half0 keys quad*4+0..3  (contraction j=0..3)
      pf.h[1] = pk[1];   // half1 keys quad*4+0..3  (contraction j=4..7)
#pragma unroll
      for (int nt = 0; nt < 4; nt++)
        o_acc[mt][nt] = __builtin_amdgcn_mfma_f32_16x16x32_bf16(pf.v, vf[nt],
                                                                o_acc[mt][nt],
                                                                0, 0, 0);
      l_acc[mt] = __builtin_amdgcn_mfma_f32_16x16x32_bf16(pf.v, vones,
                                                          l_acc[mt], 0, 0, 0);
    }
  }

  // ---- epilogue: l_acc[mt][r] = l for query mt*16+quad*4+r (dup over cl) ----
#pragma unroll
  for (int mt = 0; mt < 2; mt++)
    if (cl == 0) *(f32x4*)&Lbuf[w * 32 + mt * 16 + quad * 4] = l_acc[mt];
  __syncthreads();            // loop reads done -> smem reusable for Obuf
  if (wk == 1) {
#pragma unroll
    for (int mt = 0; mt < 2; mt++)
#pragma unroll
      for (int nt = 0; nt < 4; nt++)
        *(f32x4*)&Ob[wq * 2048 + (mt * 4 + nt) * 256 + lane * 4] = o_acc[mt][nt];
  }
  __syncthreads();
  if (wk == 0) {
#pragma unroll
    for (int mt = 0; mt < 2; mt++) {
      float linv[4];
#pragma unroll
      for (int r = 0; r < 4; r++) {
        const int ql = mt * 16 + quad * 4 + r;
        linv[r] = 1.0f / (l_acc[mt][r] + Lbuf[(wq * 2 + 1) * 32 + ql]);
      }
#pragma unroll
      for (int nt = 0; nt < 4; nt++) {
        f32x4 other = *(const f32x4*)&Ob[wq * 2048 + (mt * 4 + nt) * 256 + lane * 4];
#pragma unroll
        for (int r = 0; r < 4; r++) {
          const int q = q0 + wq * 32 + mt * 16 + quad * 4 + r;
          const int hd = nt * 16 + cl;
          Ctx[(uint64_t)(b * 2048 + q) * 1024 + h * 64 + hd] =
              (bf16)((o_acc[mt][nt][r] + other[r]) * linv[r]);
        }
      }
    }
  }
}

// ---------------------------------------------------------------------------
extern "C" void kernel_launch(void* const* d_in, const int* in_sizes, int n_in,
                              void* d_out, int out_size, void* d_ws, size_t ws_size,
                              hipStream_t stream) {
  const float* x  = (const float*)d_in[0];
  const float* Wq = (const float*)d_in[1];
  const float* Wk = (const float*)d_in[2];
  const float* Wv = (const float*)d_in[3];
  const float* Wo = (const float*)d_in[4];
  const float* qs = (const float*)d_in[5];
  const float* ks = (const float*)d_in[6];
  const float* vs = (const float*)d_in[7];
  const float* os = (const float*)d_in[8];
  float* out = (float*)d_out;

  const size_t M4 = 4194304, M1 = 1048576;

  if (ws_size >= (size_t)40 * 1024 * 1024) {
    bf16* xb = (bf16*)d_ws;        // 4M bf16; reused as cw after QKV
    bf16* wb = xb + M4;            // wq|wk|wv|wo
    bf16* qw = wb + M4;
    bf16* kw = qw + M4;
    bf16* vw = kw + M4;
    bf16* cw = xb;

    cvt_kernel<<<dim3(512, 8), 256, 0, stream>>>(x, Wq, Wk, Wv, Wo, xb, wb);
    gemm_kernel<bf16, bf16, 128><<<dim3(32, 24), 256, 0, stream>>>(
        xb, wb, wb + M1, wb + 2 * M1, qs, ks, vs, qw, kw, vw, nullptr, 1);
    attn_kernel<<<512, 512, 0, stream>>>(qw, kw, vw, cw);
    gemm_kernel<bf16, bf16, 64><<<dim3(32, 16), 256, 0, stream>>>(
        cw, wb + 3 * M1, nullptr, nullptr, os, nullptr, nullptr,
        nullptr, nullptr, nullptr, out, 0);
  } else {
    bf16* qw = (bf16*)d_ws;
    bf16* kw = qw + M4;
    bf16* vw = kw + M4;
    bf16* cw = vw + M4;
    gemm_kernel<float, float, 128><<<dim3(32, 24), 256, 0, stream>>>(
        x, Wq, Wk, Wv, qs, ks, vs, qw, kw, vw, nullptr, 1);
    attn_kernel<<<512, 512, 0, stream>>>(qw, kw, vw, cw);
    gemm_kernel<bf16, float, 64><<<dim3(32, 16), 256, 0, stream>>>(
        cw, Wo, nullptr, nullptr, os, nullptr, nullptr,
        nullptr, nullptr, nullptr, out, 0);
  }
}

// Round 12
// 171.158 us; speedup vs baseline: 1.5313x; 1.0671x over previous
//
#include <hip/hip_runtime.h>
#include <hip/hip_bf16.h>
#include <stdint.h>

// B=2, S=2048, D=1024, H=16, Hd=64.  Inputs/outputs FP32; internal bf16 MFMA.
// R22 = R21 resubmitted verbatim (R11 bench died on infra error: "container
// failed twice"; kernel untested).  R21 = R20 (182.6us) + GEMM restructure:
// (1) BK 32 -> 64: stage 64 K-cols per barrier pair (8 gl_lds/thread, 8-chunk
//     XOR swizzle chunk^(row&7) at 128B rows -- the attn kernel's proven
//     conflict-free pattern), two K=32 MFMA halves between barriers.
//     Barriers/block 64 -> 32, MFMA per barrier interval 16 -> 32.
//     Bit-identical math.  LDS 32KB/block.
// (2) gemm2 NTILE 64 -> 128 (m92->m93 lever): grid (32,8), coalesced fp32
//     epilogue (per-wave 4KB slice of As, col rotated 4*row mod 64, f32x4
//     readback, full-128B-line stores).
// attn (v12: register-P, permuted V, MFMA ones-column l) and cvt unchanged.

typedef __bf16 bf16;
typedef __attribute__((ext_vector_type(8))) __bf16 bf16x8;
typedef __attribute__((ext_vector_type(4))) __bf16 bf16x4;
typedef __attribute__((ext_vector_type(4))) float f32x4;

#define DEVI __device__ __forceinline__

DEVI void gl_lds16(const void* g, void* l) {
  __builtin_amdgcn_global_load_lds(
      (const __attribute__((address_space(1))) void*)g,
      (__attribute__((address_space(3))) void*)l, 16, 0, 0);
}

DEVI bf16x8 load8(const bf16* p) { return *(const bf16x8*)p; }
DEVI bf16x8 load8(const float* p) {
  f32x4 a = *(const f32x4*)p;
  f32x4 b = *(const f32x4*)(p + 4);
  bf16x8 r;
  r[0] = (bf16)a[0]; r[1] = (bf16)a[1]; r[2] = (bf16)a[2]; r[3] = (bf16)a[3];
  r[4] = (bf16)b[0]; r[5] = (bf16)b[1]; r[6] = (bf16)b[2]; r[7] = (bf16)b[3];
  return r;
}

// ---------------------------------------------------------------------------
// fp32 -> bf16 bulk convert.  grid (512, 8): y<4 -> W[y], y>=4 -> x quarter.
// ---------------------------------------------------------------------------
__global__ __launch_bounds__(256)
void cvt_kernel(const float* __restrict__ x,
                const float* __restrict__ w0, const float* __restrict__ w1,
                const float* __restrict__ w2, const float* __restrict__ w3,
                bf16* __restrict__ xb, bf16* __restrict__ wb) {
  const int y = blockIdx.y;
  const float* src;
  bf16* dst;
  if (y < 4) {
    src = (y == 0) ? w0 : (y == 1) ? w1 : (y == 2) ? w2 : w3;
    dst = wb + (size_t)y * 1048576;
  } else {
    src = x + (size_t)(y - 4) * 1048576;
    dst = xb + (size_t)(y - 4) * 1048576;
  }
  const int i = (blockIdx.x * 256 + threadIdx.x) * 8;
  *(bf16x8*)(dst + i) = load8(src + i);
}

// ---------------------------------------------------------------------------
// GEMM (BK=64, 128x128 tile): C[m,n] = (sum_k X[m,k]*W[n,k]) * scale[n] [*emul]
// three=1: 8 n-tiles per W; mode1 (Q/K) -> [B,H,S,64] coalesced LDS-transpose
//   epilogue (Q gets emul=0.125*log2e); mode2 (V) -> [B,H,64,S] key-permuted.
// three=0 (mode 0): fp32 row-major out via coalesced rotated-LDS epilogue.
// ---------------------------------------------------------------------------
template <typename XT, typename WT>
__global__ __launch_bounds__(256, 2)
void gemm_kernel(const XT* __restrict__ X,
                 const WT* __restrict__ W0, const WT* __restrict__ W1,
                 const WT* __restrict__ W2,
                 const float* __restrict__ s0, const float* __restrict__ s1,
                 const float* __restrict__ s2,
                 bf16* __restrict__ o0, bf16* __restrict__ o1,
                 bf16* __restrict__ o2, float* __restrict__ ofp, int three) {
  constexpr bool ASYNC_A = (sizeof(XT) == 2);
  constexpr bool ASYNC_B = (sizeof(WT) == 2);
  __shared__ bf16 As[128 * 64];    // [row][64], chunk c^(row&7)   (16 KB)
  __shared__ bf16 Bs[128 * 64];    //                              (16 KB)

  const int t = threadIdx.x;
  const int lane = t & 63;
  const int w = t >> 6;
  const int wm = w >> 1, wn = w & 1;
  const int m0 = blockIdx.x * 128;
  const int cl = lane & 15, quad = lane >> 4;

  const WT* Wp; const float* sp; bf16* op; int mode, n0; float emul = 1.f;
  if (three) {
    int which = blockIdx.y >> 3;
    n0 = (blockIdx.y & 7) * 128;
    if (which == 0)      { Wp = W0; sp = s0; op = o0; mode = 1; emul = 0.18033688f; }
    else if (which == 1) { Wp = W1; sp = s1; op = o1; mode = 1; }
    else                 { Wp = W2; sp = s2; op = o2; mode = 2; }
  } else {
    n0 = blockIdx.y * 128; Wp = W0; sp = s0; op = o0; mode = 0;
  }

  f32x4 zero = {0.f, 0.f, 0.f, 0.f};
  f32x4 acc[4][4];
#pragma unroll
  for (int i = 0; i < 4; i++)
#pragma unroll
    for (int j = 0; j < 4; j++) acc[i][j] = zero;

  // staging geometry: 1024 16B-chunks per 16KB tile; thread t, round p ->
  // chunk g = p*256+t, row = p*32 + (t>>3), phys chunk pc = t&7,
  // logical chunk lc = pc ^ (row&7)  (source pre-swizzle, LDS linear).
  const int row64 = t >> 3;                        // 0..31
  const int lc8 = (((t & 7) ^ (row64 & 7))) * 8;   // element offset of chunk

  for (int k0 = 0; k0 < 1024; k0 += 64) {
    bf16x8 av[4], bv[4];
    if constexpr (!ASYNC_A) {
#pragma unroll
      for (int p = 0; p < 4; p++)
        av[p] = load8(&X[(uint64_t)(m0 + p * 32 + row64) * 1024 + k0 + lc8]);
    }
    if constexpr (!ASYNC_B) {
#pragma unroll
      for (int p = 0; p < 4; p++)
        bv[p] = load8(&Wp[(uint64_t)(n0 + p * 32 + row64) * 1024 + k0 + lc8]);
    }
    __syncthreads();
    if constexpr (ASYNC_A) {
#pragma unroll
      for (int p = 0; p < 4; p++)
        gl_lds16(X + (uint64_t)(m0 + p * 32 + row64) * 1024 + k0 + lc8,
                 (char*)As + p * 4096 + t * 16);
    } else {
#pragma unroll
      for (int p = 0; p < 4; p++)
        *(bf16x8*)&As[(p * 32 + row64) * 64 + (t & 7) * 8] = av[p];
    }
    if constexpr (ASYNC_B) {
#pragma unroll
      for (int p = 0; p < 4; p++)
        gl_lds16(Wp + (uint64_t)(n0 + p * 32 + row64) * 1024 + k0 + lc8,
                 (char*)Bs + p * 4096 + t * 16);
    } else {
#pragma unroll
      for (int p = 0; p < 4; p++)
        *(bf16x8*)&Bs[(p * 32 + row64) * 64 + (t & 7) * 8] = bv[p];
    }
    __syncthreads();

#pragma unroll
    for (int kkh = 0; kkh < 2; kkh++) {
      bf16x8 af[4], bfr[4];
#pragma unroll
      for (int mt = 0; mt < 4; mt++) {
        const int row = wm * 64 + mt * 16 + cl;
        af[mt] = *(const bf16x8*)&As[row * 64 +
                                     (((kkh * 4 + quad) ^ (cl & 7)) << 3)];
      }
#pragma unroll
      for (int nt = 0; nt < 4; nt++) {
        const int row = wn * 64 + nt * 16 + cl;
        bfr[nt] = *(const bf16x8*)&Bs[row * 64 +
                                      (((kkh * 4 + quad) ^ (cl & 7)) << 3)];
      }
#pragma unroll
      for (int mt = 0; mt < 4; mt++)
#pragma unroll
        for (int nt = 0; nt < 4; nt++)
          acc[mt][nt] = __builtin_amdgcn_mfma_f32_16x16x32_bf16(af[mt], bfr[nt],
                                                                acc[mt][nt],
                                                                0, 0, 0);
    }
  }

  if (mode == 1) {
    // ---- coalesced LDS-transpose epilogue (Q/K) ----
    __syncthreads();   // all waves done reading As/Bs
    bf16* slice = (bf16*)((char*)As + w * 4096);
    const int h = (n0 >> 6) + wn;
    float scv[4];
#pragma unroll
    for (int nt = 0; nt < 4; nt++)
      scv[nt] = sp[n0 + wn * 64 + nt * 16 + cl] * emul;
#pragma unroll
    for (int mt = 0; mt < 4; mt++) {
#pragma unroll
      for (int nt = 0; nt < 4; nt++)
#pragma unroll
        for (int r = 0; r < 4; r++)
          slice[(quad * 4 + r) * 72 + nt * 16 + cl] =
              (bf16)(acc[mt][nt][r] * scv[nt]);
#pragma unroll
      for (int rr = 0; rr < 2; rr++) {
        const int sr = rr * 8 + (lane >> 3);
        const int hdc = (lane & 7) * 8;
        bf16x8 v = *(const bf16x8*)&slice[sr * 72 + hdc];
        const int gm = m0 + wm * 64 + mt * 16 + sr;
        const int bb = gm >> 11, ss = gm & 2047;
        *(bf16x8*)&op[((uint64_t)(bb * 16 + h) * 2048 + ss) * 64 + hdc] = v;
      }
    }
  } else if (mode == 0) {
    // ---- coalesced fp32 epilogue (Wo output) ----
    __syncthreads();   // all waves done reading As/Bs
    float* slice = (float*)((char*)As + w * 4096);   // 16x64 f32 per wave
    float scv[4];
#pragma unroll
    for (int nt = 0; nt < 4; nt++)
      scv[nt] = sp[n0 + wn * 64 + nt * 16 + cl];
#pragma unroll
    for (int mt = 0; mt < 4; mt++) {
#pragma unroll
      for (int nt = 0; nt < 4; nt++)
#pragma unroll
        for (int r = 0; r < 4; r++) {
          const int row = quad * 4 + r;
          const int col = nt * 16 + cl;
          slice[row * 64 + ((col + 4 * row) & 63)] = acc[mt][nt][r] * scv[nt];
        }
#pragma unroll
      for (int p = 0; p < 4; p++) {
        const int sr = p * 4 + quad;
        const int c4 = cl * 4;
        f32x4 v = *(const f32x4*)&slice[sr * 64 + ((c4 + 4 * sr) & 63)];
        const int gm = m0 + wm * 64 + mt * 16 + sr;
        *(f32x4*)&ofp[(uint64_t)gm * 1024 + n0 + wn * 64 + c4] = v;
      }
    }
  } else {
    // ---- mode 2 (V): scalar stores with key-permute ----
#pragma unroll
    for (int nt = 0; nt < 4; nt++) {
      const int gn = n0 + wn * 64 + nt * 16 + cl;
      const float sc = sp[gn];
#pragma unroll
      for (int mt = 0; mt < 4; mt++) {
        const int gmb = m0 + wm * 64 + mt * 16 + quad * 4;
#pragma unroll
        for (int r = 0; r < 4; r++) {
          const int gm = gmb + r;
          const float v = acc[mt][nt][r] * sc;
          const int b = gm >> 11, s = gm & 2047;
          const int h = gn >> 6, hd = gn & 63;
          // key-permute within each 32-block: p = qd*8 + knt*4 + r
          const int sp2 = (s & ~31) |
                          ((s & 3) | (((s >> 2) & 3) << 3) | (((s >> 4) & 1) << 2));
          uint64_t addr = ((uint64_t)(b * 16 + h) * 64 + hd) * 2048 + sp2;
          op[addr] = (bf16)v;
        }
      }
    }
  }
}

// ---------------------------------------------------------------------------
// Flash attention v12: 8 waves (512 threads), wave split 4x2 (wq x wk),
// single-buffered 2-barrier loop, P register-resident, V key-permuted in
// memory (single-b128 PV B-frag), softmax denominator via MFMA ones-column.
// Epilogue: cross-wave (wk) O+l combine via LDS; Obuf aliases K/V region.
// ---------------------------------------------------------------------------
__global__ __launch_bounds__(512, 4)
void attn_kernel(const bf16* __restrict__ Qw, const bf16* __restrict__ Kw,
                 const bf16* __restrict__ Vtw, bf16* __restrict__ Ctx) {
  // loop: [0,8K) Ks | [8K,16K) Vs.  epilogue: Obuf[4][2048] fp32 on [0,32K).
  __shared__ char smem[32768];
  __shared__ float Lbuf[256];           // [wq*2+wk][32 queries]

  bf16* Ks = (bf16*)smem;               // [key][d], chunk c^(key&7)
  bf16* Vs = (bf16*)(smem + 8192);      // [hd][key-permuted], chunk c^(hd&7)
  float* Ob = (float*)smem;             // epilogue alias

  const int t = threadIdx.x, lane = t & 63, w = t >> 6;
  const int cl = lane & 15, quad = lane >> 4;
  const int wq = w >> 1, wk = w & 1;

  const int id = blockIdx.x;
  const int xcd = id & 7, kk = id >> 3;
  const int bh = xcd * 4 + (kk >> 4);
  const int qt = kk & 15;
  const int b = bh >> 4, h = bh & 15;
  const int q0 = qt * 128;

  const bf16* Qh = Qw + (uint64_t)bh * 2048 * 64;
  const bf16* Kh = Kw + (uint64_t)bh * 2048 * 64;
  const bf16* Vh = Vtw + (uint64_t)bh * 64 * 2048;

  // Q B-fragments: B[k=h*32+quad*8+j][n=cl], queries q0+wq*32+mt*16+cl
  bf16x8 qf[2][2];
#pragma unroll
  for (int mt = 0; mt < 2; mt++) {
    const int r = q0 + wq * 32 + mt * 16 + cl;
    qf[mt][0] = *(const bf16x8*)&Qh[(uint64_t)r * 64 + quad * 8];
    qf[mt][1] = *(const bf16x8*)&Qh[(uint64_t)r * 64 + 32 + quad * 8];
  }

  bf16x8 vones;
#pragma unroll
  for (int j = 0; j < 8; j++) vones[j] = (bf16)1.0f;

  f32x4 zero = {0.f, 0.f, 0.f, 0.f};
  f32x4 o_acc[2][4];
  f32x4 l_acc[2];
#pragma unroll
  for (int mt = 0; mt < 2; mt++) {
    l_acc[mt] = zero;
#pragma unroll
    for (int nt = 0; nt < 4; nt++) o_acc[mt][nt] = zero;
  }

  const int srow = t >> 3;                         // 0..63
  const int gcol_sw = ((t & 7) ^ (srow & 7)) * 8;  // swizzled source col
  const int lcV = wk * 4 + quad;                   // V b128 logical chunk

  for (int k0 = 0; k0 < 2048; k0 += 64) {
    __syncthreads();
    gl_lds16(Kh + (uint64_t)(k0 + srow) * 64 + gcol_sw, (char*)Ks + t * 16);
    gl_lds16(Vh + (uint64_t)srow * 2048 + k0 + gcol_sw, (char*)Vs + t * 16);
    __syncthreads();   // tiles resident

    // K A-frags for this wave's 32-key half
    bf16x8 kf[2][2];
#pragma unroll
    for (int knt = 0; knt < 2; knt++) {
      const int krow = wk * 32 + knt * 16 + cl;
#pragma unroll
      for (int hh = 0; hh < 2; hh++)
        kf[knt][hh] = *(const bf16x8*)&Ks[krow * 64 +
                                          (((hh * 4 + quad) ^ (cl & 7)) << 3)];
    }
    // V B-frags: single b128 of permuted V (contraction units {2q,2q+1})
    bf16x8 vf[4];
#pragma unroll
    for (int nt = 0; nt < 4; nt++)
      vf[nt] = *(const bf16x8*)&Vs[(nt * 16 + cl) * 64 +
                                   ((lcV ^ (cl & 7)) << 3)];

    // Per mt: S^T (log2 units) -> exp2 -> pk (registers) -> PV + l-MFMA
#pragma unroll
    for (int mt = 0; mt < 2; mt++) {
      bf16x4 pk[2];
#pragma unroll
      for (int knt = 0; knt < 2; knt++) {
        f32x4 s = __builtin_amdgcn_mfma_f32_16x16x32_bf16(kf[knt][0], qf[mt][0],
                                                          zero, 0, 0, 0);
        s = __builtin_amdgcn_mfma_f32_16x16x32_bf16(kf[knt][1], qf[mt][1], s, 0, 0, 0);
#pragma unroll
        for (int r = 0; r < 4; r++)
          pk[knt][r] = (bf16)__builtin_amdgcn_exp2f(s[r]);
      }
      union { bf16x4 h[2]; bf16x8 v; } pf;
      pf.h[0] = pk[0];   // half0 keys quad*4+0..3  (contraction j=0..3)
      pf.h[1] = pk[1];   // half1 keys quad*4+0..3  (contraction j=4..7)
#pragma unroll
      for (int nt = 0; nt < 4; nt++)
        o_acc[mt][nt] = __builtin_amdgcn_mfma_f32_16x16x32_bf16(pf.v, vf[nt],
                                                                o_acc[mt][nt],
                                                                0, 0, 0);
      l_acc[mt] = __builtin_amdgcn_mfma_f32_16x16x32_bf16(pf.v, vones,
                                                          l_acc[mt], 0, 0, 0);
    }
  }

  // ---- epilogue: l_acc[mt][r] = l for query mt*16+quad*4+r (dup over cl) ----
#pragma unroll
  for (int mt = 0; mt < 2; mt++)
    if (cl == 0) *(f32x4*)&Lbuf[w * 32 + mt * 16 + quad * 4] = l_acc[mt];
  __syncthreads();            // loop reads done -> smem reusable for Obuf
  if (wk == 1) {
#pragma unroll
    for (int mt = 0; mt < 2; mt++)
#pragma unroll
      for (int nt = 0; nt < 4; nt++)
        *(f32x4*)&Ob[wq * 2048 + (mt * 4 + nt) * 256 + lane * 4] = o_acc[mt][nt];
  }
  __syncthreads();
  if (wk == 0) {
#pragma unroll
    for (int mt = 0; mt < 2; mt++) {
      float linv[4];
#pragma unroll
      for (int r = 0; r < 4; r++) {
        const int ql = mt * 16 + quad * 4 + r;
        linv[r] = 1.0f / (l_acc[mt][r] + Lbuf[(wq * 2 + 1) * 32 + ql]);
      }
#pragma unroll
      for (int nt = 0; nt < 4; nt++) {
        f32x4 other = *(const f32x4*)&Ob[wq * 2048 + (mt * 4 + nt) * 256 + lane * 4];
#pragma unroll
        for (int r = 0; r < 4; r++) {
          const int q = q0 + wq * 32 + mt * 16 + quad * 4 + r;
          const int hd = nt * 16 + cl;
          Ctx[(uint64_t)(b * 2048 + q) * 1024 + h * 64 + hd] =
              (bf16)((o_acc[mt][nt][r] + other[r]) * linv[r]);
        }
      }
    }
  }
}

// ---------------------------------------------------------------------------
extern "C" void kernel_launch(void* const* d_in, const int* in_sizes, int n_in,
                              void* d_out, int out_size, void* d_ws, size_t ws_size,
                              hipStream_t stream) {
  const float* x  = (const float*)d_in[0];
  const float* Wq = (const float*)d_in[1];
  const float* Wk = (const float*)d_in[2];
  const float* Wv = (const float*)d_in[3];
  const float* Wo = (const float*)d_in[4];
  const float* qs = (const float*)d_in[5];
  const float* ks = (const float*)d_in[6];
  const float* vs = (const float*)d_in[7];
  const float* os = (const float*)d_in[8];
  float* out = (float*)d_out;

  const size_t M4 = 4194304, M1 = 1048576;

  if (ws_size >= (size_t)40 * 1024 * 1024) {
    bf16* xb = (bf16*)d_ws;        // 4M bf16; reused as cw after QKV
    bf16* wb = xb + M4;            // wq|wk|wv|wo
    bf16* qw = wb + M4;
    bf16* kw = qw + M4;
    bf16* vw = kw + M4;
    bf16* cw = xb;

    cvt_kernel<<<dim3(512, 8), 256, 0, stream>>>(x, Wq, Wk, Wv, Wo, xb, wb);
    gemm_kernel<bf16, bf16><<<dim3(32, 24), 256, 0, stream>>>(
        xb, wb, wb + M1, wb + 2 * M1, qs, ks, vs, qw, kw, vw, nullptr, 1);
    attn_kernel<<<512, 512, 0, stream>>>(qw, kw, vw, cw);
    gemm_kernel<bf16, bf16><<<dim3(32, 8), 256, 0, stream>>>(
        cw, wb + 3 * M1, nullptr, nullptr, os, nullptr, nullptr,
        nullptr, nullptr, nullptr, out, 0);
  } else {
    bf16* qw = (bf16*)d_ws;
    bf16* kw = qw + M4;
    bf16* vw = kw + M4;
    bf16* cw = vw + M4;
    gemm_kernel<float, float><<<dim3(32, 24), 256, 0, stream>>>(
        x, Wq, Wk, Wv, qs, ks, vs, qw, kw, vw, nullptr, 1);
    attn_kernel<<<512, 512, 0, stream>>>(qw, kw, vw, cw);
    gemm_kernel<bf16, float><<<dim3(32, 8), 256, 0, stream>>>(
        cw, Wo, nullptr, nullptr, os, nullptr, nullptr,
        nullptr, nullptr, nullptr, out, 0);
  }
}